// Round 16
// baseline (760.802 us; speedup 1.0000x reference)
//
#include <hip/hip_runtime.h>
#include <hip/hip_bf16.h>
#include <math.h>

#define LDIM 384
#define CDIM 128
#define HN 4
#define LL (LDIM*LDIM)
#define NCHUNK 8
#define VTPLANE ((size_t)12288*384)

typedef __attribute__((ext_vector_type(8))) short bf16x8;
typedef __attribute__((ext_vector_type(4))) float f32x4;

__device__ __forceinline__ ushort f2bf(float x) {
    union { __hip_bfloat16 h; ushort u; } cv;
    cv.h = __float2bfloat16(x);
    return cv.u;
}
__device__ __forceinline__ float bf2f(ushort u) {
    union { unsigned int i; float f; } cv; cv.i = ((unsigned int)u) << 16; return cv.f;
}
// 256B-row swizzle: row-XOR spreads rows; (cb&128)>>3 folds the 128B bank-window alias
// (cb vs cb+128) onto adjacent 16B slots. Bijective; write+read both use this function.
__device__ __forceinline__ int swz256(int row, int cb) {
    return (row * 256 + cb) ^ ((row & 7) << 4) ^ ((cb & 128) >> 3);
}
__device__ __forceinline__ int swz128(int row, int cb) { return (row * 128 + cb) ^ ((row & 7) << 4); }
__device__ __forceinline__ size_t trow(int row) { return (size_t)(row % LDIM) * LDIM + row / LDIM; }

// ---------------- weight prep: fp32 [K][N] -> bf16 [N][KP] (zero-padded K) ----------------
__global__ __launch_bounds__(256) void wprep_kernel(ushort* __restrict__ wt,
    const float* emb_w, const float* proj_w,
    const float* rwq, const float* rwk, const float* rwv, const float* rwg, const float* rwo,
    const float* cwq, const float* cwk, const float* cwv, const float* cwg, const float* cwo,
    const float* ffw1, const float* ffw2)
{
    int y = blockIdx.y;
    const float* src; int N, K, KP; size_t off;
    switch (y) {
        case 0:  src = emb_w;  N = 128; K = 36;  KP = 128; off = 0;         break;
        case 1:  src = proj_w; N = 128; K = 128; KP = 128; off = 16384;     break;
        case 2:  src = rwq;    N = 128; K = 128; KP = 128; off = 2*16384;   break;
        case 3:  src = rwk;    N = 128; K = 128; KP = 128; off = 3*16384;   break;
        case 4:  src = rwv;    N = 128; K = 128; KP = 128; off = 4*16384;   break;
        case 5:  src = rwg;    N = 128; K = 128; KP = 128; off = 5*16384;   break;
        case 6:  src = rwo;    N = 128; K = 128; KP = 128; off = 6*16384;   break;
        case 7:  src = cwq;    N = 128; K = 128; KP = 128; off = 7*16384;   break;
        case 8:  src = cwk;    N = 128; K = 128; KP = 128; off = 8*16384;   break;
        case 9:  src = cwv;    N = 128; K = 128; KP = 128; off = 9*16384;   break;
        case 10: src = cwg;    N = 128; K = 128; KP = 128; off = 10*16384;  break;
        case 11: src = cwo;    N = 128; K = 128; KP = 128; off = 11*16384;  break;
        case 12: src = ffw1;   N = 256; K = 128; KP = 128; off = 12*16384;  break;
        default: src = ffw2;   N = 128; K = 256; KP = 256; off = 12*16384 + 32768; break;
    }
    int e = blockIdx.x * 256 + threadIdx.x;
    if (e >= N * KP) return;
    int nn = e / KP, kp = e - nn * KP;
    float v = (kp < K) ? src[(size_t)kp * N + nn] : 0.f;
    wt[off + e] = f2bf(v);
}

// ------- LN + bf16 pack: coalesced read of src row p, write to dst row trans(p) -------
__global__ __launch_bounds__(256) void lnpack_kernel(const float* __restrict__ src,
    ushort* __restrict__ dst, const float* __restrict__ w, const float* __restrict__ b, int trans)
{
    int p = (blockIdx.x << 2) + (threadIdx.x >> 6);
    int lane = threadIdx.x & 63;
    float2 v = *(const float2*)(src + (size_t)p * CDIM + (lane << 1));
    float s  = v.x + v.y;
    float ss = v.x*v.x + v.y*v.y;
    #pragma unroll
    for (int off = 32; off; off >>= 1) { s += __shfl_xor(s, off, 64); ss += __shfl_xor(ss, off, 64); }
    float mean = s * (1.0f/CDIM);
    float var  = ss * (1.0f/CDIM) - mean*mean;
    float rstd = rsqrtf(var + 1e-5f);
    int q = trans ? ((p % LDIM) * LDIM + p / LDIM) : p;
    ushort2 o;
    o.x = f2bf((v.x - mean) * rstd * w[lane<<1]     + b[lane<<1]);
    o.y = f2bf((v.y - mean) * rstd * w[(lane<<1)+1] + b[(lane<<1)+1]);
    *(ushort2*)(dst + (size_t)q * CDIM + (lane << 1)) = o;
}

// ------- fused proj GEMM + dual battn: C (=rbf) never materialized. -------
__global__ __launch_bounds__(256) void proj_battn_gemm(
    const ushort* __restrict__ A, const ushort* __restrict__ Wt, const float* __restrict__ pb,
    const float* __restrict__ rlnw, const float* __restrict__ rlnb, const float* __restrict__ rwb,
    const float* __restrict__ clnw, const float* __restrict__ clnb, const float* __restrict__ cwb,
    float* __restrict__ battn_r, float* __restrict__ battn_c)
{
    __shared__ ushort As[128*64];
    __shared__ ushort Ws[128*64];
    int t = threadIdx.x, l = t & 63, wv = t >> 6;
    int m0 = blockIdx.x << 7;
    int wm = (wv >> 1) << 6, wn = (wv & 1) << 6;
    int sr = t >> 1, sh = (t & 1) << 5;
    f32x4 acc[4][4] = {};
    for (int k0 = 0; k0 < 128; k0 += 64) {
        if (k0) __syncthreads();
        const ushort* ap = A + (size_t)(m0 + sr) * CDIM + k0 + sh;
        #pragma unroll
        for (int u = 0; u < 4; u++)
            *(int4*)((char*)As + swz128(sr, (sh << 1) + (u << 4))) = *(const int4*)(ap + (u << 3));
        const ushort* wp2 = Wt + (size_t)sr * CDIM + k0 + sh;
        #pragma unroll
        for (int u = 0; u < 4; u++)
            *(int4*)((char*)Ws + swz128(sr, (sh << 1) + (u << 4))) = *(const int4*)(wp2 + (u << 3));
        __syncthreads();
        #pragma unroll
        for (int ks = 0; ks < 2; ks++) {
            int kb = (ks << 6) + ((l >> 4) << 4);
            bf16x8 a[4], b[4];
            #pragma unroll
            for (int x = 0; x < 4; x++) {
                a[x] = *(const bf16x8*)((char*)As + swz128(wm + (x << 4) + (l & 15), kb));
                b[x] = *(const bf16x8*)((char*)Ws + swz128(wn + (x << 4) + (l & 15), kb));
            }
            #pragma unroll
            for (int i = 0; i < 4; i++)
            #pragma unroll
            for (int j = 0; j < 4; j++)
                acc[i][j] = __builtin_amdgcn_mfma_f32_16x16x32_bf16(a[i], b[j], acc[i][j], 0, 0, 0);
        }
    }
    int lc = l & 15, lr = l >> 4;
    float pbv[4], rlw[4], rlb[4], clw[4], clb[4];
    float4 rw4[4], cw4[4];
    #pragma unroll
    for (int nf = 0; nf < 4; nf++) {
        int col = wn + (nf << 4) + lc;
        pbv[nf] = pb[col];
        rlw[nf] = rlnw[col]; rlb[nf] = rlnb[col];
        clw[nf] = clnw[col]; clb[nf] = clnb[col];
        rw4[nf] = *(const float4*)&rwb[col * HN];
        cw4[nf] = *(const float4*)&cwb[col * HN];
    }
    float* buf  = (float*)Ws;
    float* dbuf = buf + 512;
    __syncthreads();
    #pragma unroll
    for (int mf = 0; mf < 4; mf++) {
        float v[4][4];
        #pragma unroll
        for (int r = 0; r < 4; r++)
        #pragma unroll
        for (int nf = 0; nf < 4; nf++)
            v[r][nf] = acc[mf][nf][r] + pbv[nf];
        float s[4], q[4];
        #pragma unroll
        for (int r = 0; r < 4; r++) {
            float a0 = 0.f, a1 = 0.f;
            #pragma unroll
            for (int nf = 0; nf < 4; nf++) { a0 += v[r][nf]; a1 += v[r][nf]*v[r][nf]; }
            s[r] = a0; q[r] = a1;
        }
        #pragma unroll
        for (int off = 1; off < 16; off <<= 1)
        #pragma unroll
        for (int r = 0; r < 4; r++) {
            s[r] += __shfl_xor(s[r], off, 64);
            q[r] += __shfl_xor(q[r], off, 64);
        }
        if (lc == 0) {
            #pragma unroll
            for (int r = 0; r < 4; r++) {
                int rl = wm + (mf << 4) + (lr << 2) + r;
                buf[(((wv & 1) << 7) + rl) * 2 + 0] = s[r];
                buf[(((wv & 1) << 7) + rl) * 2 + 1] = q[r];
            }
        }
        __syncthreads();
        float p[4][8];
        #pragma unroll
        for (int r = 0; r < 4; r++) {
            int rl = wm + (mf << 4) + (lr << 2) + r;
            float S = buf[rl * 2 + 0] + buf[(256 + rl * 2) + 0];
            float Q = buf[rl * 2 + 1] + buf[(256 + rl * 2) + 1];
            float mean = S * (1.f/CDIM);
            float var  = Q * (1.f/CDIM) - mean * mean;
            float rstd = rsqrtf(var + 1e-5f);
            float p0=0.f,p1=0.f,p2=0.f,p3=0.f,p4=0.f,p5=0.f,p6=0.f,p7=0.f;
            #pragma unroll
            for (int nf = 0; nf < 4; nf++) {
                float cn = (v[r][nf] - mean) * rstd;
                float xr = cn * rlw[nf] + rlb[nf];
                float xc = cn * clw[nf] + clb[nf];
                p0 += xr * rw4[nf].x; p1 += xr * rw4[nf].y;
                p2 += xr * rw4[nf].z; p3 += xr * rw4[nf].w;
                p4 += xc * cw4[nf].x; p5 += xc * cw4[nf].y;
                p6 += xc * cw4[nf].z; p7 += xc * cw4[nf].w;
            }
            p[r][0]=p0; p[r][1]=p1; p[r][2]=p2; p[r][3]=p3;
            p[r][4]=p4; p[r][5]=p5; p[r][6]=p6; p[r][7]=p7;
        }
        #pragma unroll
        for (int off = 1; off < 16; off <<= 1)
        #pragma unroll
        for (int r = 0; r < 4; r++)
        #pragma unroll
        for (int i = 0; i < 8; i++)
            p[r][i] += __shfl_xor(p[r][i], off, 64);
        if (wn == 0 && lc == 0) {
            #pragma unroll
            for (int r = 0; r < 4; r++) {
                int rl = wm + (mf << 4) + (lr << 2) + r;
                #pragma unroll
                for (int i = 0; i < 8; i++) dbuf[rl * 8 + i] = p[r][i];
            }
        }
        __syncthreads();
        if (wn == 64 && lc == 0) {
            #pragma unroll
            for (int r = 0; r < 4; r++) {
                int rl = wm + (mf << 4) + (lr << 2) + r;
                int rowg = m0 + rl;
                int a = rowg / LDIM, b2 = rowg % LDIM;
                #pragma unroll
                for (int h = 0; h < HN; h++) {
                    battn_r[((size_t)h*LDIM + b2)*LDIM + a]  = p[r][h]   + dbuf[rl*8 + h];
                    battn_c[((size_t)h*LDIM + a)*LDIM + b2]  = p[r][4+h] + dbuf[rl*8 + 4 + h];
                }
            }
        }
    }
}

// ------- BK=64 128x128-tile MFMA GEMM (round-7 verified config). -------
template<int ACT, int AMODE, int OUTMODE, int LNOUT>
__global__ __launch_bounds__(256) void mgemm64(
    const void* __restrict__ Ain, const ushort* __restrict__ Wt,
    const float* __restrict__ bias, const ushort* __restrict__ gmul,
    const float* __restrict__ res, void* __restrict__ Cout,
    const float* __restrict__ lnw2, const float* __restrict__ lnb2, ushort* __restrict__ xln,
    int N, int KP, int lda, float alpha, int rtrans, int otrans)
{
    __shared__ ushort As[128*64];
    __shared__ ushort Ws[128*64];
    int t = threadIdx.x, l = t & 63, wv = t >> 6;
    int m0 = blockIdx.y << 7, n0 = blockIdx.x << 7;
    int wm = (wv >> 1) << 6, wn = (wv & 1) << 6;
    int sr = t >> 1;
    int sh = (t & 1) << 5;
    f32x4 acc[4][4] = {};
    for (int k0 = 0; k0 < KP; k0 += 64) {
        if (k0) __syncthreads();
        if (AMODE == 1) {
            const ushort* ap = (const ushort*)Ain + (size_t)(m0 + sr) * lda + k0 + sh;
            #pragma unroll
            for (int u = 0; u < 4; u++)
                *(int4*)((char*)As + swz128(sr, (sh << 1) + (u << 4))) = *(const int4*)(ap + (u << 3));
        } else if (AMODE == 2) {
            const ushort* ap = (const ushort*)Ain + (size_t)(m0 + sr) * lda + k0 + sh;
            const ushort* gp = gmul + (size_t)(m0 + sr) * lda + k0 + sh;
            #pragma unroll
            for (int u = 0; u < 4; u++) {
                int4 av = *(const int4*)(ap + (u << 3));
                int4 gv = *(const int4*)(gp + (u << 3));
                ushort* au = (ushort*)&av; ushort* gu = (ushort*)&gv;
                short v8[8];
                #pragma unroll
                for (int e = 0; e < 8; e++) v8[e] = (short)f2bf(bf2f(au[e]) * bf2f(gu[e]));
                *(int4*)((char*)As + swz128(sr, (sh << 1) + (u << 4))) = *(int4*)v8;
            }
        } else {
            const float* ap = (const float*)Ain + (size_t)(m0 + sr) * lda;
            #pragma unroll
            for (int u = 0; u < 4; u++) {
                short v8[8];
                #pragma unroll
                for (int e = 0; e < 8; e++) {
                    int c = k0 + sh + (u << 3) + e;
                    v8[e] = (short)f2bf((c < lda) ? ap[c] : 0.f);
                }
                *(int4*)((char*)As + swz128(sr, (sh << 1) + (u << 4))) = *(int4*)v8;
            }
        }
        {
            const ushort* wp2 = Wt + (size_t)(n0 + sr) * KP + k0 + sh;
            #pragma unroll
            for (int u = 0; u < 4; u++)
                *(int4*)((char*)Ws + swz128(sr, (sh << 1) + (u << 4))) = *(const int4*)(wp2 + (u << 3));
        }
        __syncthreads();
        #pragma unroll
        for (int ks = 0; ks < 2; ks++) {
            int kb = (ks << 6) + ((l >> 4) << 4);
            bf16x8 a[4], b[4];
            #pragma unroll
            for (int x = 0; x < 4; x++) {
                a[x] = *(const bf16x8*)((char*)As + swz128(wm + (x << 4) + (l & 15), kb));
                b[x] = *(const bf16x8*)((char*)Ws + swz128(wn + (x << 4) + (l & 15), kb));
            }
            #pragma unroll
            for (int i = 0; i < 4; i++)
            #pragma unroll
            for (int j = 0; j < 4; j++)
                acc[i][j] = __builtin_amdgcn_mfma_f32_16x16x32_bf16(a[i], b[j], acc[i][j], 0, 0, 0);
        }
    }
    if (LNOUT) {
        #pragma unroll
        for (int mf = 0; mf < 4; mf++)
        #pragma unroll
        for (int nf = 0; nf < 4; nf++) {
            int col  = wn + (nf << 4) + (l & 15);
            int row0 = m0 + wm + (mf << 4) + ((l >> 4) << 2);
            float bb = bias ? bias[col] : 0.f;
            #pragma unroll
            for (int r = 0; r < 4; r++) {
                int row = row0 + r;
                size_t rrow = rtrans ? trow(row) : (size_t)row;
                acc[mf][nf][r] = acc[mf][nf][r] * alpha + bb + (res ? res[rrow * CDIM + col] : 0.f);
            }
        }
        float ps[4][4], pq[4][4];
        #pragma unroll
        for (int mf = 0; mf < 4; mf++)
        #pragma unroll
        for (int r = 0; r < 4; r++) {
            float s = 0.f, q = 0.f;
            #pragma unroll
            for (int nf = 0; nf < 4; nf++) { float v = acc[mf][nf][r]; s += v; q += v * v; }
            ps[mf][r] = s; pq[mf][r] = q;
        }
        #pragma unroll
        for (int off = 1; off < 16; off <<= 1)
        #pragma unroll
        for (int mf = 0; mf < 4; mf++)
        #pragma unroll
        for (int r = 0; r < 4; r++) {
            ps[mf][r] += __shfl_xor(ps[mf][r], off, 64);
            pq[mf][r] += __shfl_xor(pq[mf][r], off, 64);
        }
        __syncthreads();
        float* lnbuf = (float*)As;
        if ((l & 15) == 0) {
            #pragma unroll
            for (int mf = 0; mf < 4; mf++)
            #pragma unroll
            for (int r = 0; r < 4; r++) {
                int rl = wm + (mf << 4) + ((l >> 4) << 2) + r;
                lnbuf[(((wv & 1) << 7) + rl) * 2 + 0] = ps[mf][r];
                lnbuf[(((wv & 1) << 7) + rl) * 2 + 1] = pq[mf][r];
            }
        }
        __syncthreads();
        #pragma unroll
        for (int mf = 0; mf < 4; mf++)
        #pragma unroll
        for (int nf = 0; nf < 4; nf++) {
            int col  = wn + (nf << 4) + (l & 15);
            int row0 = m0 + wm + (mf << 4) + ((l >> 4) << 2);
            float lw = lnw2[col], lb = lnb2[col];
            #pragma unroll
            for (int r = 0; r < 4; r++) {
                int row = row0 + r;
                int rl  = wm + (mf << 4) + ((l >> 4) << 2) + r;
                float s  = lnbuf[rl * 2 + 0] + lnbuf[(256 + rl * 2) + 0];
                float q  = lnbuf[rl * 2 + 1] + lnbuf[(256 + rl * 2) + 1];
                float mean = s * (1.f/CDIM);
                float var  = q * (1.f/CDIM) - mean * mean;
                float rstd = rsqrtf(var + 1e-5f);
                float o = acc[mf][nf][r];
                size_t orow = otrans ? trow(row) : (size_t)row;
                ((float*)Cout)[orow * CDIM + col] = o;
                xln[orow * CDIM + col] = f2bf((o - mean) * rstd * lw + lb);
            }
        }
    } else {
        #pragma unroll
        for (int mf = 0; mf < 4; mf++)
        #pragma unroll
        for (int nf = 0; nf < 4; nf++) {
            int col  = n0 + wn + (nf << 4) + (l & 15);
            int row0 = m0 + wm + (mf << 4) + ((l >> 4) << 2);
            float bb = bias ? bias[col] : 0.f;
            #pragma unroll
            for (int r = 0; r < 4; r++) {
                int row = row0 + r;
                float v = acc[mf][nf][r] * alpha + bb;
                if (ACT == 1) v = fmaxf(v, 0.f);
                if (ACT == 2) v = 1.f / (1.f + __expf(-v));
                if (OUTMODE == 0) {
                    float o = v + (res ? res[(size_t)row * N + col] : 0.f);
                    ((float*)Cout)[(size_t)row * N + col] = o;
                } else if (OUTMODE == 1) {
                    ((ushort*)Cout)[(size_t)row * N + col] = f2bf(v);
                } else {
                    size_t orow = otrans ? trow(row) : (size_t)row;
                    size_t rrow = rtrans ? trow(row) : (size_t)row;
                    float o = v + (res ? res[rrow * N + col] : 0.f);
                    ((float*)Cout)[orow * N + col] = o;
                }
            }
        }
    }
}

// ------- q,k,v,g: M=64 tile (As 16KB + Ws 32KB = 48KB -> 3 blocks/CU), 2304 blocks -------
__global__ __launch_bounds__(256) void qkv4_gemm(
    const ushort* __restrict__ A, const ushort* __restrict__ wt4,
    ushort* __restrict__ qo, ushort* __restrict__ ko, ushort* __restrict__ vt,
    ushort* __restrict__ go, const float* __restrict__ bg,
    float scale_q, float scale_k)
{
    __shared__ ushort As[64*128];
    __shared__ ushort Ws[128*128];
    int t = threadIdx.x, l = t & 63, wv = t >> 6;
    int m0 = blockIdx.x << 6;
    int wm = (wv >> 1) << 5;
    int wn = (wv & 1) << 6;
    {
        int sr = t >> 2, scb = (t & 3) << 6;
        const ushort* ap = A + (size_t)(m0 + sr) * CDIM + (scb >> 1);
        #pragma unroll
        for (int u = 0; u < 4; u++)
            *(int4*)((char*)As + swz256(sr, scb + (u << 4))) = *(const int4*)(ap + (u << 3));
    }
    for (int comp = 0; comp < 4; comp++) {
        if (comp) __syncthreads();
        {
            int sr = t >> 1, scb = (t & 1) << 7;
            const ushort* wp2 = wt4 + (size_t)comp * 16384 + (size_t)sr * CDIM + (scb >> 1);
            #pragma unroll
            for (int u = 0; u < 8; u++)
                *(int4*)((char*)Ws + swz256(sr, scb + (u << 4))) = *(const int4*)(wp2 + (u << 3));
        }
        __syncthreads();
        f32x4 acc[2][4] = {};
        #pragma unroll
        for (int ks = 0; ks < 4; ks++) {
            int kb = (ks << 6) + ((l >> 4) << 4);
            bf16x8 a[2], b[4];
            #pragma unroll
            for (int x = 0; x < 2; x++)
                a[x] = *(const bf16x8*)((char*)As + swz256(wm + (x << 4) + (l & 15), kb));
            #pragma unroll
            for (int x = 0; x < 4; x++)
                b[x] = *(const bf16x8*)((char*)Ws + swz256(wn + (x << 4) + (l & 15), kb));
            #pragma unroll
            for (int i = 0; i < 2; i++)
            #pragma unroll
            for (int j = 0; j < 4; j++)
                acc[i][j] = __builtin_amdgcn_mfma_f32_16x16x32_bf16(a[i], b[j], acc[i][j], 0, 0, 0);
        }
        #pragma unroll
        for (int mf = 0; mf < 2; mf++)
        #pragma unroll
        for (int nf = 0; nf < 4; nf++) {
            int col  = wn + (nf << 4) + (l & 15);
            int row0 = m0 + wm + (mf << 4) + ((l >> 4) << 2);
            if (comp == 0) {
                #pragma unroll
                for (int r = 0; r < 4; r++)
                    qo[(size_t)(row0 + r) * CDIM + col] = f2bf(acc[mf][nf][r] * scale_q);
            } else if (comp == 1) {
                #pragma unroll
                for (int r = 0; r < 4; r++)
                    ko[(size_t)(row0 + r) * CDIM + col] = f2bf(acc[mf][nf][r] * scale_k);
            } else if (comp == 2) {
                ushort4 pk;
                #pragma unroll
                for (int r = 0; r < 4; r++) ((ushort*)&pk)[r] = f2bf(acc[mf][nf][r]);
                int n = row0 / LDIM, j = row0 % LDIM;
                *(ushort4*)&vt[((size_t)(col >> 5) * 12288 + (size_t)n * 32 + (col & 31)) * 384 + j] = pk;
            } else {
                float bb = bg[col];
                #pragma unroll
                for (int r = 0; r < 4; r++) {
                    float v = acc[mf][nf][r] + bb;
                    go[(size_t)(row0 + r) * CDIM + col] = f2bf(1.f / (1.f + __expf(-v)));
                }
            }
        }
    }
}

// ------- tied scores (verified round-7 3D grid): partial[cz,h,i,j] -------
__global__ __launch_bounds__(256) void score128(const ushort* __restrict__ Q,
    const ushort* __restrict__ Kb, float* __restrict__ partial)
{
    __shared__ ushort As[128*128];
    __shared__ ushort Bs[128*128];
    int t = threadIdx.x, l = t & 63, wv = t >> 6;
    int ti = blockIdx.x / 3, tj = blockIdx.x % 3;
    int h = blockIdx.y, cz = blockIdx.z;
    int i0 = ti << 7, j0 = tj << 7;
    int wm = (wv >> 1) << 6, wn = (wv & 1) << 6;
    int sr = t >> 1, half = t & 1;
    f32x4 acc[4][4] = {};
    for (int it = 0; it < 12; it++) {
        if (it) __syncthreads();
        int nb = cz * 48 + (it << 2);
        #pragma unroll
        for (int e = 0; e < 2; e++) {
            int nq = (half << 1) + e;
            const ushort* qp = Q  + ((size_t)(nb + nq) * LDIM + i0 + sr) * CDIM + (h << 5);
            const ushort* kp = Kb + ((size_t)(nb + nq) * LDIM + j0 + sr) * CDIM + (h << 5);
            *(int4*)((char*)As + swz256(sr, (nq << 6) +  0)) = *(const int4*)qp;
            *(int4*)((char*)As + swz256(sr, (nq << 6) + 16)) = *(const int4*)(qp + 8);
            *(int4*)((char*)As + swz256(sr, (nq << 6) + 32)) = *(const int4*)(qp + 16);
            *(int4*)((char*)As + swz256(sr, (nq << 6) + 48)) = *(const int4*)(qp + 24);
            *(int4*)((char*)Bs + swz256(sr, (nq << 6) +  0)) = *(const int4*)kp;
            *(int4*)((char*)Bs + swz256(sr, (nq << 6) + 16)) = *(const int4*)(kp + 8);
            *(int4*)((char*)Bs + swz256(sr, (nq << 6) + 32)) = *(const int4*)(kp + 16);
            *(int4*)((char*)Bs + swz256(sr, (nq << 6) + 48)) = *(const int4*)(kp + 24);
        }
        __syncthreads();
        #pragma unroll
        for (int ks = 0; ks < 4; ks++) {
            int kb = (ks << 6) + ((l >> 4) << 4);
            bf16x8 a[4], b[4];
            #pragma unroll
            for (int x = 0; x < 4; x++) {
                a[x] = *(const bf16x8*)((char*)As + swz256(wm + (x << 4) + (l & 15), kb));
                b[x] = *(const bf16x8*)((char*)Bs + swz256(wn + (x << 4) + (l & 15), kb));
            }
            #pragma unroll
            for (int i = 0; i < 4; i++)
            #pragma unroll
            for (int j = 0; j < 4; j++)
                acc[i][j] = __builtin_amdgcn_mfma_f32_16x16x32_bf16(a[i], b[j], acc[i][j], 0, 0, 0);
        }
    }
    #pragma unroll
    for (int mf = 0; mf < 4; mf++)
    #pragma unroll
    for (int nf = 0; nf < 4; nf++) {
        int j = j0 + wn + (nf << 4) + (l & 15);
        int i = i0 + wm + (mf << 4) + ((l >> 4) << 2);
        #pragma unroll
        for (int r = 0; r < 4; r++)
            partial[((size_t)(cz*HN + h)*LDIM + i + r)*LDIM + j] = acc[mf][nf][r];
    }
}

// ---------------- softmax over j (chunk reduce + bias) -> bf16 ----------------
__global__ __launch_bounds__(64) void softmax_kernel(
    const float* __restrict__ partial, const float* __restrict__ battn, ushort* __restrict__ attn)
{
    int hi = blockIdx.x;
    int l = threadIdx.x;
    float s[6];
    #pragma unroll
    for (int u = 0; u < 6; u++) {
        size_t idx = (size_t)hi * LDIM + l + (u << 6);
        float v = battn[idx];
        #pragma unroll
        for (int c = 0; c < NCHUNK; c++) v += partial[(size_t)c * HN * LL + idx];
        s[u] = v;
    }
    float m = s[0];
    #pragma unroll
    for (int u = 1; u < 6; u++) m = fmaxf(m, s[u]);
    #pragma unroll
    for (int off = 32; off; off >>= 1) m = fmaxf(m, __shfl_xor(m, off, 64));
    float sum = 0.f;
    #pragma unroll
    for (int u = 0; u < 6; u++) { s[u] = __expf(s[u] - m); sum += s[u]; }
    #pragma unroll
    for (int off = 32; off; off >>= 1) sum += __shfl_xor(sum, off, 64);
    float inv = 1.f / sum;
    #pragma unroll
    for (int u = 0; u < 6; u++) attn[(size_t)hi * LDIM + l + (u << 6)] = f2bf(s[u] * inv);
}

// ------- PV per-head GEMM (BK=64): pvout[(n,i),h*32+d] -------
__global__ __launch_bounds__(256) void pvg_gemm(const ushort* __restrict__ attn,
    const ushort* __restrict__ vt, ushort* __restrict__ pvout)
{
    __shared__ ushort As[128*64];
    __shared__ ushort Ws[128*64];
    int t = threadIdx.x, l = t & 63, wv = t >> 6;
    int n0 = blockIdx.x << 7;
    int i0 = blockIdx.y << 7;
    int h  = blockIdx.z;
    const ushort* abase = attn + (size_t)h * LL;
    const ushort* bbase = vt + (size_t)h * VTPLANE;
    int wm = (wv >> 1) << 6, wn = (wv & 1) << 6;
    int sr = t >> 1, sh = (t & 1) << 5;
    f32x4 acc[4][4] = {};
    for (int k0 = 0; k0 < LDIM; k0 += 64) {
        if (k0) __syncthreads();
        {
            const ushort* ap = abase + (size_t)(i0 + sr) * LDIM + k0 + sh;
            const ushort* bp = bbase + (size_t)(n0 + sr) * LDIM + k0 + sh;
            #pragma unroll
            for (int u = 0; u < 4; u++) {
                *(int4*)((char*)As + swz128(sr, (sh << 1) + (u << 4))) = *(const int4*)(ap + (u << 3));
                *(int4*)((char*)Ws + swz128(sr, (sh << 1) + (u << 4))) = *(const int4*)(bp + (u << 3));
            }
        }
        __syncthreads();
        #pragma unroll
        for (int ks = 0; ks < 2; ks++) {
            int kb = (ks << 6) + ((l >> 4) << 4);
            bf16x8 a[4], b[4];
            #pragma unroll
            for (int x = 0; x < 4; x++) {
                a[x] = *(const bf16x8*)((char*)As + swz128(wm + (x << 4) + (l & 15), kb));
                b[x] = *(const bf16x8*)((char*)Ws + swz128(wn + (x << 4) + (l & 15), kb));
            }
            #pragma unroll
            for (int i = 0; i < 4; i++)
            #pragma unroll
            for (int j = 0; j < 4; j++)
                acc[i][j] = __builtin_amdgcn_mfma_f32_16x16x32_bf16(a[i], b[j], acc[i][j], 0, 0, 0);
        }
    }
    #pragma unroll
    for (int mf = 0; mf < 4; mf++)
    #pragma unroll
    for (int nf = 0; nf < 4; nf++) {
        int col  = n0 + wn + (nf << 4) + (l & 15);
        int row0 = i0 + wm + (mf << 4) + ((l >> 4) << 2);
        int n = col >> 5, d = col & 31;
        #pragma unroll
        for (int r = 0; r < 4; r++) {
            int i = row0 + r;
            pvout[((size_t)n * LDIM + i) * CDIM + (h << 5) + d] = f2bf(acc[mf][nf][r]);
        }
    }
}

extern "C" void kernel_launch(void* const* d_in, const int* in_sizes, int n_in,
                              void* d_out, int out_size, void* d_ws, size_t ws_size,
                              hipStream_t stream)
{
    const float* pair     = (const float*)d_in[0];
    const float* rbf_feat = (const float*)d_in[1];
    const float* emb_b    = (const float*)d_in[3];
    const float* proj_b   = (const float*)d_in[5];
    const float* ff_ln_w  = (const float*)d_in[30];
    const float* ff_ln_b  = (const float*)d_in[31];
    const float* ff_b1    = (const float*)d_in[33];
    const float* ff_b2    = (const float*)d_in[35];
    float* out = (float*)d_out;

    ushort* R0 = (ushort*)d_ws;
    ushort* R1 = R0 + (size_t)LL*CDIM;
    ushort* R2 = R1 + (size_t)LL*CDIM;
    ushort* R3 = R2 + (size_t)LL*CDIM;
    float*  partialb = (float*)(R3 + (size_t)LL*CDIM);
    float*  battn_r  = partialb + (size_t)NCHUNK*HN*LL;
    float*  battn_c  = battn_r  + (size_t)HN*LL;
    ushort* attn_bf  = (ushort*)(battn_c + (size_t)HN*LL);
    ushort* wt       = attn_bf + (size_t)HN*LL;

    size_t need_bytes = (size_t)4*LL*CDIM*2 + ((size_t)NCHUNK*HN*LL + 2*(size_t)HN*LL)*4
                      + (size_t)HN*LL*2 + (size_t)262144*2;
    if (ws_size < need_bytes) return;

    const size_t WS = 16384;
    ushort* wt_emb  = wt;
    ushort* wt_proj = wt + WS;
    ushort* wt_ff1  = wt + 12*WS;
    ushort* wt_ff2  = wt + 12*WS + 32768;

    const float SCALE = 0.17677669529663687f;  // 32^-0.5

    wprep_kernel<<<dim3(128, 14), 256, 0, stream>>>(wt,
        (const float*)d_in[2], (const float*)d_in[4],
        (const float*)d_in[10], (const float*)d_in[11], (const float*)d_in[12],
        (const float*)d_in[14], (const float*)d_in[16],
        (const float*)d_in[22], (const float*)d_in[23], (const float*)d_in[24],
        (const float*)d_in[26], (const float*)d_in[28],
        (const float*)d_in[32], (const float*)d_in[34]);

    // emb hidden bf16 -> R3
    mgemm64<1,0,1,0><<<dim3(1,1152), 256, 0, stream>>>(rbf_feat, wt_emb, emb_b, nullptr, nullptr, R3,
        nullptr, nullptr, nullptr, 128, 128, 36, 1.f, 0, 0);
    // fused proj + dual battn: rbf never materialized
    proj_battn_gemm<<<1152, 256, 0, stream>>>(R3, wt_proj, proj_b,
        (const float*)d_in[8],  (const float*)d_in[9],  (const float*)d_in[13],
        (const float*)d_in[20], (const float*)d_in[21], (const float*)d_in[25],
        battn_r, battn_c);

    // initial row-pass xln (transposed frame) -> R3
    lnpack_kernel<<<LL/4, 256, 0, stream>>>(pair, R3, (const float*)d_in[6], (const float*)d_in[7], 1);

    ushort* XLN = R3;
    for (int pass = 0; pass < 2; pass++) {
        const float* const* wp = (const float* const*)(d_in + (pass ? 18 : 6));
        int trans = pass ? 0 : 1;
        const float* P = pass ? (const float*)out : pair;
        const float* battnb = pass ? battn_c : battn_r;
        int ws0 = pass ? 7 : 2;
        const float* nlw = pass ? ff_ln_w : (const float*)d_in[18];
        const float* nlb = pass ? ff_ln_b : (const float*)d_in[19];
        ushort* Qb   = R0;
        ushort* Kb2  = pass ? R3 : R1;
        ushort* VTb  = R2;
        ushort* PVb  = R0;
        ushort* XLNn = pass ? R3 : R1;
        qkv4_gemm<<<LL/64, 256, 0, stream>>>(XLN, wt + ws0*WS, Qb, Kb2, VTb, XLN, wp[9], SCALE, 1.f/LDIM);
        score128<<<dim3(9, HN, NCHUNK), 256, 0, stream>>>(Qb, Kb2, partialb);
        softmax_kernel<<<HN*LDIM, 64, 0, stream>>>(partialb, battnb, attn_bf);
        pvg_gemm<<<dim3(96, 3, 4), 256, 0, stream>>>(attn_bf, VTb, PVb);
        mgemm64<0,2,3,1><<<dim3(1,1152), 256, 0, stream>>>(PVb, wt + (ws0+4)*WS, wp[11], XLN, P, out,
            nlw, nlb, XLNn, 128, 128, 128, 1.f, trans, trans);
        XLN = XLNn;
    }

    // FFN: out += relu(xln@w1+b1)@w2+b2  (h1 bf16 [LL][256] spans R0+R1)
    mgemm64<1,1,1,0><<<dim3(2,1152), 256, 0, stream>>>(XLN, wt_ff1, ff_b1, nullptr, nullptr, R0,
        nullptr, nullptr, nullptr, 256, 128, 128, 1.f, 0, 0);
    mgemm64<0,1,0,0><<<dim3(1,1152), 256, 0, stream>>>(R0, wt_ff2, ff_b2, nullptr, out, out,
        nullptr, nullptr, nullptr, 128, 256, 256, 1.f, 0, 0);
}

// Round 17
// 696.832 us; speedup vs baseline: 1.0918x; 1.0918x over previous
//
#include <hip/hip_runtime.h>
#include <hip/hip_bf16.h>
#include <math.h>

#define LDIM 384
#define CDIM 128
#define HN 4
#define LL (LDIM*LDIM)
#define NCHUNK 8
#define VTPLANE ((size_t)12288*384)

typedef __attribute__((ext_vector_type(8))) short bf16x8;
typedef __attribute__((ext_vector_type(4))) float f32x4;

__device__ __forceinline__ ushort f2bf(float x) {
    union { __hip_bfloat16 h; ushort u; } cv;
    cv.h = __float2bfloat16(x);
    return cv.u;
}
__device__ __forceinline__ float bf2f(ushort u) {
    union { unsigned int i; float f; } cv; cv.i = ((unsigned int)u) << 16; return cv.f;
}
__device__ __forceinline__ int swz256(int row, int cb) {
    return (row * 256 + cb) ^ ((row & 7) << 4) ^ ((cb & 128) >> 3);
}
__device__ __forceinline__ int swz128(int row, int cb) { return (row * 128 + cb) ^ ((row & 7) << 4); }
__device__ __forceinline__ size_t trow(int row) { return (size_t)(row % LDIM) * LDIM + row / LDIM; }

// ---------------- weight prep: fp32 [K][N] -> bf16 [N][KP] (zero-padded K) ----------------
__global__ __launch_bounds__(256) void wprep_kernel(ushort* __restrict__ wt,
    const float* emb_w, const float* proj_w,
    const float* rwq, const float* rwk, const float* rwv, const float* rwg, const float* rwo,
    const float* cwq, const float* cwk, const float* cwv, const float* cwg, const float* cwo,
    const float* ffw1, const float* ffw2)
{
    int y = blockIdx.y;
    const float* src; int N, K, KP; size_t off;
    switch (y) {
        case 0:  src = emb_w;  N = 128; K = 36;  KP = 128; off = 0;         break;
        case 1:  src = proj_w; N = 128; K = 128; KP = 128; off = 16384;     break;
        case 2:  src = rwq;    N = 128; K = 128; KP = 128; off = 2*16384;   break;
        case 3:  src = rwk;    N = 128; K = 128; KP = 128; off = 3*16384;   break;
        case 4:  src = rwv;    N = 128; K = 128; KP = 128; off = 4*16384;   break;
        case 5:  src = rwg;    N = 128; K = 128; KP = 128; off = 5*16384;   break;
        case 6:  src = rwo;    N = 128; K = 128; KP = 128; off = 6*16384;   break;
        case 7:  src = cwq;    N = 128; K = 128; KP = 128; off = 7*16384;   break;
        case 8:  src = cwk;    N = 128; K = 128; KP = 128; off = 8*16384;   break;
        case 9:  src = cwv;    N = 128; K = 128; KP = 128; off = 9*16384;   break;
        case 10: src = cwg;    N = 128; K = 128; KP = 128; off = 10*16384;  break;
        case 11: src = cwo;    N = 128; K = 128; KP = 128; off = 11*16384;  break;
        case 12: src = ffw1;   N = 256; K = 128; KP = 128; off = 12*16384;  break;
        default: src = ffw2;   N = 128; K = 256; KP = 256; off = 12*16384 + 32768; break;
    }
    int e = blockIdx.x * 256 + threadIdx.x;
    if (e >= N * KP) return;
    int nn = e / KP, kp = e - nn * KP;
    float v = (kp < K) ? src[(size_t)kp * N + nn] : 0.f;
    wt[off + e] = f2bf(v);
}

// ------- LN + bf16 pack: coalesced read of src row p, write to dst row trans(p) -------
__global__ __launch_bounds__(256) void lnpack_kernel(const float* __restrict__ src,
    ushort* __restrict__ dst, const float* __restrict__ w, const float* __restrict__ b, int trans)
{
    int p = (blockIdx.x << 2) + (threadIdx.x >> 6);
    int lane = threadIdx.x & 63;
    float2 v = *(const float2*)(src + (size_t)p * CDIM + (lane << 1));
    float s  = v.x + v.y;
    float ss = v.x*v.x + v.y*v.y;
    #pragma unroll
    for (int off = 32; off; off >>= 1) { s += __shfl_xor(s, off, 64); ss += __shfl_xor(ss, off, 64); }
    float mean = s * (1.0f/CDIM);
    float var  = ss * (1.0f/CDIM) - mean*mean;
    float rstd = rsqrtf(var + 1e-5f);
    int q = trans ? ((p % LDIM) * LDIM + p / LDIM) : p;
    ushort2 o;
    o.x = f2bf((v.x - mean) * rstd * w[lane<<1]     + b[lane<<1]);
    o.y = f2bf((v.y - mean) * rstd * w[(lane<<1)+1] + b[(lane<<1)+1]);
    *(ushort2*)(dst + (size_t)q * CDIM + (lane << 1)) = o;
}

// ------- fused proj GEMM + dual battn (verified r15 structure, M=128) -------
__global__ __launch_bounds__(256) void proj_battn_gemm(
    const ushort* __restrict__ A, const ushort* __restrict__ Wt, const float* __restrict__ pb,
    const float* __restrict__ rlnw, const float* __restrict__ rlnb, const float* __restrict__ rwb,
    const float* __restrict__ clnw, const float* __restrict__ clnb, const float* __restrict__ cwb,
    float* __restrict__ battn_r, float* __restrict__ battn_c)
{
    __shared__ ushort As[128*64];
    __shared__ ushort Ws[128*64];
    int t = threadIdx.x, l = t & 63, wv = t >> 6;
    int m0 = blockIdx.x << 7;
    int wm = (wv >> 1) << 6, wn = (wv & 1) << 6;
    int sr = t >> 1, sh = (t & 1) << 5;
    f32x4 acc[4][4] = {};
    for (int k0 = 0; k0 < 128; k0 += 64) {
        if (k0) __syncthreads();
        const ushort* ap = A + (size_t)(m0 + sr) * CDIM + k0 + sh;
        #pragma unroll
        for (int u = 0; u < 4; u++)
            *(int4*)((char*)As + swz128(sr, (sh << 1) + (u << 4))) = *(const int4*)(ap + (u << 3));
        const ushort* wp2 = Wt + (size_t)sr * CDIM + k0 + sh;
        #pragma unroll
        for (int u = 0; u < 4; u++)
            *(int4*)((char*)Ws + swz128(sr, (sh << 1) + (u << 4))) = *(const int4*)(wp2 + (u << 3));
        __syncthreads();
        #pragma unroll
        for (int ks = 0; ks < 2; ks++) {
            int kb = (ks << 6) + ((l >> 4) << 4);
            bf16x8 a[4], b[4];
            #pragma unroll
            for (int x = 0; x < 4; x++) {
                a[x] = *(const bf16x8*)((char*)As + swz128(wm + (x << 4) + (l & 15), kb));
                b[x] = *(const bf16x8*)((char*)Ws + swz128(wn + (x << 4) + (l & 15), kb));
            }
            #pragma unroll
            for (int i = 0; i < 4; i++)
            #pragma unroll
            for (int j = 0; j < 4; j++)
                acc[i][j] = __builtin_amdgcn_mfma_f32_16x16x32_bf16(a[i], b[j], acc[i][j], 0, 0, 0);
        }
    }
    int lc = l & 15, lr = l >> 4;
    float pbv[4], rlw[4], rlb[4], clw[4], clb[4];
    float4 rw4[4], cw4[4];
    #pragma unroll
    for (int nf = 0; nf < 4; nf++) {
        int col = wn + (nf << 4) + lc;
        pbv[nf] = pb[col];
        rlw[nf] = rlnw[col]; rlb[nf] = rlnb[col];
        clw[nf] = clnw[col]; clb[nf] = clnb[col];
        rw4[nf] = *(const float4*)&rwb[col * HN];
        cw4[nf] = *(const float4*)&cwb[col * HN];
    }
    float* buf  = (float*)Ws;
    float* dbuf = buf + 512;
    __syncthreads();
    #pragma unroll
    for (int mf = 0; mf < 4; mf++) {
        float v[4][4];
        #pragma unroll
        for (int r = 0; r < 4; r++)
        #pragma unroll
        for (int nf = 0; nf < 4; nf++)
            v[r][nf] = acc[mf][nf][r] + pbv[nf];
        float s[4], q[4];
        #pragma unroll
        for (int r = 0; r < 4; r++) {
            float a0 = 0.f, a1 = 0.f;
            #pragma unroll
            for (int nf = 0; nf < 4; nf++) { a0 += v[r][nf]; a1 += v[r][nf]*v[r][nf]; }
            s[r] = a0; q[r] = a1;
        }
        #pragma unroll
        for (int off = 1; off < 16; off <<= 1)
        #pragma unroll
        for (int r = 0; r < 4; r++) {
            s[r] += __shfl_xor(s[r], off, 64);
            q[r] += __shfl_xor(q[r], off, 64);
        }
        if (lc == 0) {
            #pragma unroll
            for (int r = 0; r < 4; r++) {
                int rl = wm + (mf << 4) + (lr << 2) + r;
                buf[(((wv & 1) << 7) + rl) * 2 + 0] = s[r];
                buf[(((wv & 1) << 7) + rl) * 2 + 1] = q[r];
            }
        }
        __syncthreads();
        float p[4][8];
        #pragma unroll
        for (int r = 0; r < 4; r++) {
            int rl = wm + (mf << 4) + (lr << 2) + r;
            float S = buf[rl * 2 + 0] + buf[(256 + rl * 2) + 0];
            float Q = buf[rl * 2 + 1] + buf[(256 + rl * 2) + 1];
            float mean = S * (1.f/CDIM);
            float var  = Q * (1.f/CDIM) - mean * mean;
            float rstd = rsqrtf(var + 1e-5f);
            float p0=0.f,p1=0.f,p2=0.f,p3=0.f,p4=0.f,p5=0.f,p6=0.f,p7=0.f;
            #pragma unroll
            for (int nf = 0; nf < 4; nf++) {
                float cn = (v[r][nf] - mean) * rstd;
                float xr = cn * rlw[nf] + rlb[nf];
                float xc = cn * clw[nf] + clb[nf];
                p0 += xr * rw4[nf].x; p1 += xr * rw4[nf].y;
                p2 += xr * rw4[nf].z; p3 += xr * rw4[nf].w;
                p4 += xc * cw4[nf].x; p5 += xc * cw4[nf].y;
                p6 += xc * cw4[nf].z; p7 += xc * cw4[nf].w;
            }
            p[r][0]=p0; p[r][1]=p1; p[r][2]=p2; p[r][3]=p3;
            p[r][4]=p4; p[r][5]=p5; p[r][6]=p6; p[r][7]=p7;
        }
        #pragma unroll
        for (int off = 1; off < 16; off <<= 1)
        #pragma unroll
        for (int r = 0; r < 4; r++)
        #pragma unroll
        for (int i = 0; i < 8; i++)
            p[r][i] += __shfl_xor(p[r][i], off, 64);
        if (wn == 0 && lc == 0) {
            #pragma unroll
            for (int r = 0; r < 4; r++) {
                int rl = wm + (mf << 4) + (lr << 2) + r;
                #pragma unroll
                for (int i = 0; i < 8; i++) dbuf[rl * 8 + i] = p[r][i];
            }
        }
        __syncthreads();
        if (wn == 64 && lc == 0) {
            #pragma unroll
            for (int r = 0; r < 4; r++) {
                int rl = wm + (mf << 4) + (lr << 2) + r;
                int rowg = m0 + rl;
                int a = rowg / LDIM, b2 = rowg % LDIM;
                #pragma unroll
                for (int h = 0; h < HN; h++) {
                    battn_r[((size_t)h*LDIM + b2)*LDIM + a]  = p[r][h]   + dbuf[rl*8 + h];
                    battn_c[((size_t)h*LDIM + a)*LDIM + b2]  = p[r][4+h] + dbuf[rl*8 + 4 + h];
                }
            }
        }
    }
}

// ------- M=64 retiled GEMM (As 8KB + Ws 16KB = 24KB; acc[2][4]; grid.y = LL/64). -------
// AMODE: 0 fp32, 1 bf16, 2 bf16 gated. OUTMODE: 0 fp32 (+res), 1 bf16, 3 fp32 w/ rtrans/otrans.
// LNOUT: fuse LN over 128 out channels (N=128, grid.x=1, OUTMODE3): writes out fp32 + xln bf16.
template<int ACT, int AMODE, int OUTMODE, int LNOUT>
__global__ __launch_bounds__(256) void mgemm64(
    const void* __restrict__ Ain, const ushort* __restrict__ Wt,
    const float* __restrict__ bias, const ushort* __restrict__ gmul,
    const float* __restrict__ res, void* __restrict__ Cout,
    const float* __restrict__ lnw2, const float* __restrict__ lnb2, ushort* __restrict__ xln,
    int N, int KP, int lda, float alpha, int rtrans, int otrans)
{
    __shared__ ushort As[64*64];     // 8 KB
    __shared__ ushort Ws[128*64];    // 16 KB
    int t = threadIdx.x, l = t & 63, wv = t >> 6;
    int m0 = blockIdx.y << 6, n0 = blockIdx.x << 7;
    int wm = (wv >> 1) << 5;         // 0 / 32
    int wn = (wv & 1) << 6;          // 0 / 64
    int asr = t >> 2, ash = (t & 3) << 4;   // A: 4 threads/row, 16 shorts each
    int wsr = t >> 1, wsh = (t & 1) << 5;   // W: 2 threads/row, 32 shorts each
    f32x4 acc[2][4] = {};
    for (int k0 = 0; k0 < KP; k0 += 64) {
        if (k0) __syncthreads();
        if (AMODE == 1) {
            const ushort* ap = (const ushort*)Ain + (size_t)(m0 + asr) * lda + k0 + ash;
            *(int4*)((char*)As + swz128(asr, (ash << 1)))      = *(const int4*)ap;
            *(int4*)((char*)As + swz128(asr, (ash << 1) + 16)) = *(const int4*)(ap + 8);
        } else if (AMODE == 2) {
            const ushort* ap = (const ushort*)Ain + (size_t)(m0 + asr) * lda + k0 + ash;
            const ushort* gp = gmul + (size_t)(m0 + asr) * lda + k0 + ash;
            #pragma unroll
            for (int u = 0; u < 2; u++) {
                int4 av = *(const int4*)(ap + (u << 3));
                int4 gv = *(const int4*)(gp + (u << 3));
                ushort* au = (ushort*)&av; ushort* gu = (ushort*)&gv;
                short v8[8];
                #pragma unroll
                for (int e = 0; e < 8; e++) v8[e] = (short)f2bf(bf2f(au[e]) * bf2f(gu[e]));
                *(int4*)((char*)As + swz128(asr, (ash << 1) + (u << 4))) = *(int4*)v8;
            }
        } else {
            const float* ap = (const float*)Ain + (size_t)(m0 + asr) * lda;
            #pragma unroll
            for (int u = 0; u < 2; u++) {
                short v8[8];
                #pragma unroll
                for (int e = 0; e < 8; e++) {
                    int c = k0 + ash + (u << 3) + e;
                    v8[e] = (short)f2bf((c < lda) ? ap[c] : 0.f);
                }
                *(int4*)((char*)As + swz128(asr, (ash << 1) + (u << 4))) = *(int4*)v8;
            }
        }
        {
            const ushort* wp2 = Wt + (size_t)(n0 + wsr) * KP + k0 + wsh;
            #pragma unroll
            for (int u = 0; u < 4; u++)
                *(int4*)((char*)Ws + swz128(wsr, (wsh << 1) + (u << 4))) = *(const int4*)(wp2 + (u << 3));
        }
        __syncthreads();
        #pragma unroll
        for (int ks = 0; ks < 2; ks++) {
            int kb = (ks << 6) + ((l >> 4) << 4);
            bf16x8 a[2], b[4];
            #pragma unroll
            for (int x = 0; x < 2; x++)
                a[x] = *(const bf16x8*)((char*)As + swz128(wm + (x << 4) + (l & 15), kb));
            #pragma unroll
            for (int x = 0; x < 4; x++)
                b[x] = *(const bf16x8*)((char*)Ws + swz128(wn + (x << 4) + (l & 15), kb));
            #pragma unroll
            for (int i = 0; i < 2; i++)
            #pragma unroll
            for (int j = 0; j < 4; j++)
                acc[i][j] = __builtin_amdgcn_mfma_f32_16x16x32_bf16(a[i], b[j], acc[i][j], 0, 0, 0);
        }
    }
    if (LNOUT) {
        #pragma unroll
        for (int mf = 0; mf < 2; mf++)
        #pragma unroll
        for (int nf = 0; nf < 4; nf++) {
            int col  = wn + (nf << 4) + (l & 15);
            int row0 = m0 + wm + (mf << 4) + ((l >> 4) << 2);
            float bb = bias ? bias[col] : 0.f;
            #pragma unroll
            for (int r = 0; r < 4; r++) {
                int row = row0 + r;
                size_t rrow = rtrans ? trow(row) : (size_t)row;
                acc[mf][nf][r] = acc[mf][nf][r] * alpha + bb + (res ? res[rrow * CDIM + col] : 0.f);
            }
        }
        float ps[2][4], pq[2][4];
        #pragma unroll
        for (int mf = 0; mf < 2; mf++)
        #pragma unroll
        for (int r = 0; r < 4; r++) {
            float s = 0.f, q = 0.f;
            #pragma unroll
            for (int nf = 0; nf < 4; nf++) { float v = acc[mf][nf][r]; s += v; q += v * v; }
            ps[mf][r] = s; pq[mf][r] = q;
        }
        #pragma unroll
        for (int off = 1; off < 16; off <<= 1)
        #pragma unroll
        for (int mf = 0; mf < 2; mf++)
        #pragma unroll
        for (int r = 0; r < 4; r++) {
            ps[mf][r] += __shfl_xor(ps[mf][r], off, 64);
            pq[mf][r] += __shfl_xor(pq[mf][r], off, 64);
        }
        __syncthreads();
        float* lnbuf = (float*)As;       // [2][64][2] = 256 floats
        if ((l & 15) == 0) {
            #pragma unroll
            for (int mf = 0; mf < 2; mf++)
            #pragma unroll
            for (int r = 0; r < 4; r++) {
                int rl = wm + (mf << 4) + ((l >> 4) << 2) + r;
                lnbuf[(((wv & 1) << 6) + rl) * 2 + 0] = ps[mf][r];
                lnbuf[(((wv & 1) << 6) + rl) * 2 + 1] = pq[mf][r];
            }
        }
        __syncthreads();
        #pragma unroll
        for (int mf = 0; mf < 2; mf++)
        #pragma unroll
        for (int nf = 0; nf < 4; nf++) {
            int col  = wn + (nf << 4) + (l & 15);
            int row0 = m0 + wm + (mf << 4) + ((l >> 4) << 2);
            float lw = lnw2[col], lb = lnb2[col];
            #pragma unroll
            for (int r = 0; r < 4; r++) {
                int row = row0 + r;
                int rl  = wm + (mf << 4) + ((l >> 4) << 2) + r;
                float s  = lnbuf[rl * 2 + 0] + lnbuf[(128 + rl * 2) + 0];
                float q  = lnbuf[rl * 2 + 1] + lnbuf[(128 + rl * 2) + 1];
                float mean = s * (1.f/CDIM);
                float var  = q * (1.f/CDIM) - mean * mean;
                float rstd = rsqrtf(var + 1e-5f);
                float o = acc[mf][nf][r];
                size_t orow = otrans ? trow(row) : (size_t)row;
                ((float*)Cout)[orow * CDIM + col] = o;
                xln[orow * CDIM + col] = f2bf((o - mean) * rstd * lw + lb);
            }
        }
    } else {
        #pragma unroll
        for (int mf = 0; mf < 2; mf++)
        #pragma unroll
        for (int nf = 0; nf < 4; nf++) {
            int col  = n0 + wn + (nf << 4) + (l & 15);
            int row0 = m0 + wm + (mf << 4) + ((l >> 4) << 2);
            float bb = bias ? bias[col] : 0.f;
            #pragma unroll
            for (int r = 0; r < 4; r++) {
                int row = row0 + r;
                float v = acc[mf][nf][r] * alpha + bb;
                if (ACT == 1) v = fmaxf(v, 0.f);
                if (ACT == 2) v = 1.f / (1.f + __expf(-v));
                if (OUTMODE == 0) {
                    float o = v + (res ? res[(size_t)row * N + col] : 0.f);
                    ((float*)Cout)[(size_t)row * N + col] = o;
                } else if (OUTMODE == 1) {
                    ((ushort*)Cout)[(size_t)row * N + col] = f2bf(v);
                } else {
                    size_t orow = otrans ? trow(row) : (size_t)row;
                    size_t rrow = rtrans ? trow(row) : (size_t)row;
                    float o = v + (res ? res[rrow * N + col] : 0.f);
                    ((float*)Cout)[orow * N + col] = o;
                }
            }
        }
    }
}

// ------- q,k,v,g: M=64 tile (verified r13 structure) -------
__global__ __launch_bounds__(256) void qkv4_gemm(
    const ushort* __restrict__ A, const ushort* __restrict__ wt4,
    ushort* __restrict__ qo, ushort* __restrict__ ko, ushort* __restrict__ vt,
    ushort* __restrict__ go, const float* __restrict__ bg,
    float scale_q, float scale_k)
{
    __shared__ ushort As[64*128];
    __shared__ ushort Ws[128*128];
    int t = threadIdx.x, l = t & 63, wv = t >> 6;
    int m0 = blockIdx.x << 6;
    int wm = (wv >> 1) << 5;
    int wn = (wv & 1) << 6;
    {
        int sr = t >> 2, scb = (t & 3) << 6;
        const ushort* ap = A + (size_t)(m0 + sr) * CDIM + (scb >> 1);
        #pragma unroll
        for (int u = 0; u < 4; u++)
            *(int4*)((char*)As + swz256(sr, scb + (u << 4))) = *(const int4*)(ap + (u << 3));
    }
    for (int comp = 0; comp < 4; comp++) {
        if (comp) __syncthreads();
        {
            int sr = t >> 1, scb = (t & 1) << 7;
            const ushort* wp2 = wt4 + (size_t)comp * 16384 + (size_t)sr * CDIM + (scb >> 1);
            #pragma unroll
            for (int u = 0; u < 8; u++)
                *(int4*)((char*)Ws + swz256(sr, scb + (u << 4))) = *(const int4*)(wp2 + (u << 3));
        }
        __syncthreads();
        f32x4 acc[2][4] = {};
        #pragma unroll
        for (int ks = 0; ks < 4; ks++) {
            int kb = (ks << 6) + ((l >> 4) << 4);
            bf16x8 a[2], b[4];
            #pragma unroll
            for (int x = 0; x < 2; x++)
                a[x] = *(const bf16x8*)((char*)As + swz256(wm + (x << 4) + (l & 15), kb));
            #pragma unroll
            for (int x = 0; x < 4; x++)
                b[x] = *(const bf16x8*)((char*)Ws + swz256(wn + (x << 4) + (l & 15), kb));
            #pragma unroll
            for (int i = 0; i < 2; i++)
            #pragma unroll
            for (int j = 0; j < 4; j++)
                acc[i][j] = __builtin_amdgcn_mfma_f32_16x16x32_bf16(a[i], b[j], acc[i][j], 0, 0, 0);
        }
        #pragma unroll
        for (int mf = 0; mf < 2; mf++)
        #pragma unroll
        for (int nf = 0; nf < 4; nf++) {
            int col  = wn + (nf << 4) + (l & 15);
            int row0 = m0 + wm + (mf << 4) + ((l >> 4) << 2);
            if (comp == 0) {
                #pragma unroll
                for (int r = 0; r < 4; r++)
                    qo[(size_t)(row0 + r) * CDIM + col] = f2bf(acc[mf][nf][r] * scale_q);
            } else if (comp == 1) {
                #pragma unroll
                for (int r = 0; r < 4; r++)
                    ko[(size_t)(row0 + r) * CDIM + col] = f2bf(acc[mf][nf][r] * scale_k);
            } else if (comp == 2) {
                ushort4 pk;
                #pragma unroll
                for (int r = 0; r < 4; r++) ((ushort*)&pk)[r] = f2bf(acc[mf][nf][r]);
                int n = row0 / LDIM, j = row0 % LDIM;
                *(ushort4*)&vt[((size_t)(col >> 5) * 12288 + (size_t)n * 32 + (col & 31)) * 384 + j] = pk;
            } else {
                float bb = bg[col];
                #pragma unroll
                for (int r = 0; r < 4; r++) {
                    float v = acc[mf][nf][r] + bb;
                    go[(size_t)(row0 + r) * CDIM + col] = f2bf(1.f / (1.f + __expf(-v)));
                }
            }
        }
    }
}

// ------- tied scores (verified round-7 3D grid): partial[cz,h,i,j] -------
__global__ __launch_bounds__(256) void score128(const ushort* __restrict__ Q,
    const ushort* __restrict__ Kb, float* __restrict__ partial)
{
    __shared__ ushort As[128*128];
    __shared__ ushort Bs[128*128];
    int t = threadIdx.x, l = t & 63, wv = t >> 6;
    int ti = blockIdx.x / 3, tj = blockIdx.x % 3;
    int h = blockIdx.y, cz = blockIdx.z;
    int i0 = ti << 7, j0 = tj << 7;
    int wm = (wv >> 1) << 6, wn = (wv & 1) << 6;
    int sr = t >> 1, half = t & 1;
    f32x4 acc[4][4] = {};
    for (int it = 0; it < 12; it++) {
        if (it) __syncthreads();
        int nb = cz * 48 + (it << 2);
        #pragma unroll
        for (int e = 0; e < 2; e++) {
            int nq = (half << 1) + e;
            const ushort* qp = Q  + ((size_t)(nb + nq) * LDIM + i0 + sr) * CDIM + (h << 5);
            const ushort* kp = Kb + ((size_t)(nb + nq) * LDIM + j0 + sr) * CDIM + (h << 5);
            *(int4*)((char*)As + swz256(sr, (nq << 6) +  0)) = *(const int4*)qp;
            *(int4*)((char*)As + swz256(sr, (nq << 6) + 16)) = *(const int4*)(qp + 8);
            *(int4*)((char*)As + swz256(sr, (nq << 6) + 32)) = *(const int4*)(qp + 16);
            *(int4*)((char*)As + swz256(sr, (nq << 6) + 48)) = *(const int4*)(qp + 24);
            *(int4*)((char*)Bs + swz256(sr, (nq << 6) +  0)) = *(const int4*)kp;
            *(int4*)((char*)Bs + swz256(sr, (nq << 6) + 16)) = *(const int4*)(kp + 8);
            *(int4*)((char*)Bs + swz256(sr, (nq << 6) + 32)) = *(const int4*)(kp + 16);
            *(int4*)((char*)Bs + swz256(sr, (nq << 6) + 48)) = *(const int4*)(kp + 24);
        }
        __syncthreads();
        #pragma unroll
        for (int ks = 0; ks < 4; ks++) {
            int kb = (ks << 6) + ((l >> 4) << 4);
            bf16x8 a[4], b[4];
            #pragma unroll
            for (int x = 0; x < 4; x++) {
                a[x] = *(const bf16x8*)((char*)As + swz256(wm + (x << 4) + (l & 15), kb));
                b[x] = *(const bf16x8*)((char*)Bs + swz256(wn + (x << 4) + (l & 15), kb));
            }
            #pragma unroll
            for (int i = 0; i < 4; i++)
            #pragma unroll
            for (int j = 0; j < 4; j++)
                acc[i][j] = __builtin_amdgcn_mfma_f32_16x16x32_bf16(a[i], b[j], acc[i][j], 0, 0, 0);
        }
    }
    #pragma unroll
    for (int mf = 0; mf < 4; mf++)
    #pragma unroll
    for (int nf = 0; nf < 4; nf++) {
        int j = j0 + wn + (nf << 4) + (l & 15);
        int i = i0 + wm + (mf << 4) + ((l >> 4) << 2);
        #pragma unroll
        for (int r = 0; r < 4; r++)
            partial[((size_t)(cz*HN + h)*LDIM + i + r)*LDIM + j] = acc[mf][nf][r];
    }
}

// ---------------- softmax over j (chunk reduce + bias) -> bf16 ----------------
__global__ __launch_bounds__(64) void softmax_kernel(
    const float* __restrict__ partial, const float* __restrict__ battn, ushort* __restrict__ attn)
{
    int hi = blockIdx.x;
    int l = threadIdx.x;
    float s[6];
    #pragma unroll
    for (int u = 0; u < 6; u++) {
        size_t idx = (size_t)hi * LDIM + l + (u << 6);
        float v = battn[idx];
        #pragma unroll
        for (int c = 0; c < NCHUNK; c++) v += partial[(size_t)c * HN * LL + idx];
        s[u] = v;
    }
    float m = s[0];
    #pragma unroll
    for (int u = 1; u < 6; u++) m = fmaxf(m, s[u]);
    #pragma unroll
    for (int off = 32; off; off >>= 1) m = fmaxf(m, __shfl_xor(m, off, 64));
    float sum = 0.f;
    #pragma unroll
    for (int u = 0; u < 6; u++) { s[u] = __expf(s[u] - m); sum += s[u]; }
    #pragma unroll
    for (int off = 32; off; off >>= 1) sum += __shfl_xor(sum, off, 64);
    float inv = 1.f / sum;
    #pragma unroll
    for (int u = 0; u < 6; u++) attn[(size_t)hi * LDIM + l + (u << 6)] = f2bf(s[u] * inv);
}

// ------- PV per-head GEMM (BK=64): pvout[(n,i),h*32+d] -------
__global__ __launch_bounds__(256) void pvg_gemm(const ushort* __restrict__ attn,
    const ushort* __restrict__ vt, ushort* __restrict__ pvout)
{
    __shared__ ushort As[128*64];
    __shared__ ushort Ws[128*64];
    int t = threadIdx.x, l = t & 63, wv = t >> 6;
    int n0 = blockIdx.x << 7;
    int i0 = blockIdx.y << 7;
    int h  = blockIdx.z;
    const ushort* abase = attn + (size_t)h * LL;
    const ushort* bbase = vt + (size_t)h * VTPLANE;
    int wm = (wv >> 1) << 6, wn = (wv & 1) << 6;
    int sr = t >> 1, sh = (t & 1) << 5;
    f32x4 acc[4][4] = {};
    for (int k0 = 0; k0 < LDIM; k0 += 64) {
        if (k0) __syncthreads();
        {
            const ushort* ap = abase + (size_t)(i0 + sr) * LDIM + k0 + sh;
            const ushort* bp = bbase + (size_t)(n0 + sr) * LDIM + k0 + sh;
            #pragma unroll
            for (int u = 0; u < 4; u++) {
                *(int4*)((char*)As + swz128(sr, (sh << 1) + (u << 4))) = *(const int4*)(ap + (u << 3));
                *(int4*)((char*)Ws + swz128(sr, (sh << 1) + (u << 4))) = *(const int4*)(bp + (u << 3));
            }
        }
        __syncthreads();
        #pragma unroll
        for (int ks = 0; ks < 2; ks++) {
            int kb = (ks << 6) + ((l >> 4) << 4);
            bf16x8 a[4], b[4];
            #pragma unroll
            for (int x = 0; x < 4; x++) {
                a[x] = *(const bf16x8*)((char*)As + swz128(wm + (x << 4) + (l & 15), kb));
                b[x] = *(const bf16x8*)((char*)Ws + swz128(wn + (x << 4) + (l & 15), kb));
            }
            #pragma unroll
            for (int i = 0; i < 4; i++)
            #pragma unroll
            for (int j = 0; j < 4; j++)
                acc[i][j] = __builtin_amdgcn_mfma_f32_16x16x32_bf16(a[i], b[j], acc[i][j], 0, 0, 0);
        }
    }
    #pragma unroll
    for (int mf = 0; mf < 4; mf++)
    #pragma unroll
    for (int nf = 0; nf < 4; nf++) {
        int col  = n0 + wn + (nf << 4) + (l & 15);
        int row0 = i0 + wm + (mf << 4) + ((l >> 4) << 2);
        int n = col >> 5, d = col & 31;
        #pragma unroll
        for (int r = 0; r < 4; r++) {
            int i = row0 + r;
            pvout[((size_t)n * LDIM + i) * CDIM + (h << 5) + d] = f2bf(acc[mf][nf][r]);
        }
    }
}

extern "C" void kernel_launch(void* const* d_in, const int* in_sizes, int n_in,
                              void* d_out, int out_size, void* d_ws, size_t ws_size,
                              hipStream_t stream)
{
    const float* pair     = (const float*)d_in[0];
    const float* rbf_feat = (const float*)d_in[1];
    const float* emb_b    = (const float*)d_in[3];
    const float* proj_b   = (const float*)d_in[5];
    const float* ff_ln_w  = (const float*)d_in[30];
    const float* ff_ln_b  = (const float*)d_in[31];
    const float* ff_b1    = (const float*)d_in[33];
    const float* ff_b2    = (const float*)d_in[35];
    float* out = (float*)d_out;

    ushort* R0 = (ushort*)d_ws;
    ushort* R1 = R0 + (size_t)LL*CDIM;
    ushort* R2 = R1 + (size_t)LL*CDIM;
    ushort* R3 = R2 + (size_t)LL*CDIM;
    float*  partialb = (float*)(R3 + (size_t)LL*CDIM);
    float*  battn_r  = partialb + (size_t)NCHUNK*HN*LL;
    float*  battn_c  = battn_r  + (size_t)HN*LL;
    ushort* attn_bf  = (ushort*)(battn_c + (size_t)HN*LL);
    ushort* wt       = attn_bf + (size_t)HN*LL;

    size_t need_bytes = (size_t)4*LL*CDIM*2 + ((size_t)NCHUNK*HN*LL + 2*(size_t)HN*LL)*4
                      + (size_t)HN*LL*2 + (size_t)262144*2;
    if (ws_size < need_bytes) return;

    const size_t WS = 16384;
    ushort* wt_emb  = wt;
    ushort* wt_proj = wt + WS;
    ushort* wt_ff1  = wt + 12*WS;
    ushort* wt_ff2  = wt + 12*WS + 32768;

    const float SCALE = 0.17677669529663687f;  // 32^-0.5

    wprep_kernel<<<dim3(128, 14), 256, 0, stream>>>(wt,
        (const float*)d_in[2], (const float*)d_in[4],
        (const float*)d_in[10], (const float*)d_in[11], (const float*)d_in[12],
        (const float*)d_in[14], (const float*)d_in[16],
        (const float*)d_in[22], (const float*)d_in[23], (const float*)d_in[24],
        (const float*)d_in[26], (const float*)d_in[28],
        (const float*)d_in[32], (const float*)d_in[34]);

    // emb hidden bf16 -> R3
    mgemm64<1,0,1,0><<<dim3(1,LL/64), 256, 0, stream>>>(rbf_feat, wt_emb, emb_b, nullptr, nullptr, R3,
        nullptr, nullptr, nullptr, 128, 128, 36, 1.f, 0, 0);
    // fused proj + dual battn: rbf never materialized
    proj_battn_gemm<<<1152, 256, 0, stream>>>(R3, wt_proj, proj_b,
        (const float*)d_in[8],  (const float*)d_in[9],  (const float*)d_in[13],
        (const float*)d_in[20], (const float*)d_in[21], (const float*)d_in[25],
        battn_r, battn_c);

    // initial row-pass xln (transposed frame) -> R3
    lnpack_kernel<<<LL/4, 256, 0, stream>>>(pair, R3, (const float*)d_in[6], (const float*)d_in[7], 1);

    ushort* XLN = R3;
    for (int pass = 0; pass < 2; pass++) {
        const float* const* wp = (const float* const*)(d_in + (pass ? 18 : 6));
        int trans = pass ? 0 : 1;
        const float* P = pass ? (const float*)out : pair;
        const float* battnb = pass ? battn_c : battn_r;
        int ws0 = pass ? 7 : 2;
        const float* nlw = pass ? ff_ln_w : (const float*)d_in[18];
        const float* nlb = pass ? ff_ln_b : (const float*)d_in[19];
        ushort* Qb   = R0;
        ushort* Kb2  = pass ? R3 : R1;
        ushort* VTb  = R2;
        ushort* PVb  = R0;
        ushort* XLNn = pass ? R3 : R1;
        qkv4_gemm<<<LL/64, 256, 0, stream>>>(XLN, wt + ws0*WS, Qb, Kb2, VTb, XLN, wp[9], SCALE, 1.f/LDIM);
        score128<<<dim3(9, HN, NCHUNK), 256, 0, stream>>>(Qb, Kb2, partialb);
        softmax_kernel<<<HN*LDIM, 64, 0, stream>>>(partialb, battnb, attn_bf);
        pvg_gemm<<<dim3(96, 3, 4), 256, 0, stream>>>(attn_bf, VTb, PVb);
        mgemm64<0,2,3,1><<<dim3(1,LL/64), 256, 0, stream>>>(PVb, wt + (ws0+4)*WS, wp[11], XLN, P, out,
            nlw, nlb, XLNn, 128, 128, 128, 1.f, trans, trans);
        XLN = XLNn;
    }

    // FFN: out += relu(xln@w1+b1)@w2+b2  (h1 bf16 [LL][256] spans R0+R1)
    mgemm64<1,1,1,0><<<dim3(2,LL/64), 256, 0, stream>>>(XLN, wt_ff1, ff_b1, nullptr, nullptr, R0,
        nullptr, nullptr, nullptr, 256, 128, 128, 1.f, 0, 0);
    mgemm64<0,1,0,0><<<dim3(1,LL/64), 256, 0, stream>>>(R0, wt_ff2, ff_b2, nullptr, out, out,
        nullptr, nullptr, nullptr, 128, 256, 256, 1.f, 0, 0);
}

// Round 18
// 692.466 us; speedup vs baseline: 1.0987x; 1.0063x over previous
//
#include <hip/hip_runtime.h>
#include <hip/hip_bf16.h>
#include <math.h>

#define LDIM 384
#define CDIM 128
#define HN 4
#define LL (LDIM*LDIM)
#define NCHUNK 8
#define VTPLANE ((size_t)12288*384)

typedef __attribute__((ext_vector_type(8))) short bf16x8;
typedef __attribute__((ext_vector_type(4))) float f32x4;

__device__ __forceinline__ ushort f2bf(float x) {
    union { __hip_bfloat16 h; ushort u; } cv;
    cv.h = __float2bfloat16(x);
    return cv.u;
}
__device__ __forceinline__ float bf2f(ushort u) {
    union { unsigned int i; float f; } cv; cv.i = ((unsigned int)u) << 16; return cv.f;
}
__device__ __forceinline__ int swz256(int row, int cb) {
    return (row * 256 + cb) ^ ((row & 7) << 4) ^ ((cb & 128) >> 3);
}
__device__ __forceinline__ int swz128(int row, int cb) { return (row * 128 + cb) ^ ((row & 7) << 4); }
__device__ __forceinline__ size_t trow(int row) { return (size_t)(row % LDIM) * LDIM + row / LDIM; }

// ---------------- weight prep: fp32 [K][N] -> bf16 [N][KP] (zero-padded K) ----------------
__global__ __launch_bounds__(256) void wprep_kernel(ushort* __restrict__ wt,
    const float* emb_w, const float* proj_w,
    const float* rwq, const float* rwk, const float* rwv, const float* rwg, const float* rwo,
    const float* cwq, const float* cwk, const float* cwv, const float* cwg, const float* cwo,
    const float* ffw1, const float* ffw2)
{
    int y = blockIdx.y;
    const float* src; int N, K, KP; size_t off;
    switch (y) {
        case 0:  src = emb_w;  N = 128; K = 36;  KP = 128; off = 0;         break;
        case 1:  src = proj_w; N = 128; K = 128; KP = 128; off = 16384;     break;
        case 2:  src = rwq;    N = 128; K = 128; KP = 128; off = 2*16384;   break;
        case 3:  src = rwk;    N = 128; K = 128; KP = 128; off = 3*16384;   break;
        case 4:  src = rwv;    N = 128; K = 128; KP = 128; off = 4*16384;   break;
        case 5:  src = rwg;    N = 128; K = 128; KP = 128; off = 5*16384;   break;
        case 6:  src = rwo;    N = 128; K = 128; KP = 128; off = 6*16384;   break;
        case 7:  src = cwq;    N = 128; K = 128; KP = 128; off = 7*16384;   break;
        case 8:  src = cwk;    N = 128; K = 128; KP = 128; off = 8*16384;   break;
        case 9:  src = cwv;    N = 128; K = 128; KP = 128; off = 9*16384;   break;
        case 10: src = cwg;    N = 128; K = 128; KP = 128; off = 10*16384;  break;
        case 11: src = cwo;    N = 128; K = 128; KP = 128; off = 11*16384;  break;
        case 12: src = ffw1;   N = 256; K = 128; KP = 128; off = 12*16384;  break;
        default: src = ffw2;   N = 128; K = 256; KP = 256; off = 12*16384 + 32768; break;
    }
    int e = blockIdx.x * 256 + threadIdx.x;
    if (e >= N * KP) return;
    int nn = e / KP, kp = e - nn * KP;
    float v = (kp < K) ? src[(size_t)kp * N + nn] : 0.f;
    wt[off + e] = f2bf(v);
}

// ------- LN + bf16 pack: coalesced read of src row p, write to dst row trans(p) -------
__global__ __launch_bounds__(256) void lnpack_kernel(const float* __restrict__ src,
    ushort* __restrict__ dst, const float* __restrict__ w, const float* __restrict__ b, int trans)
{
    int p = (blockIdx.x << 2) + (threadIdx.x >> 6);
    int lane = threadIdx.x & 63;
    float2 v = *(const float2*)(src + (size_t)p * CDIM + (lane << 1));
    float s  = v.x + v.y;
    float ss = v.x*v.x + v.y*v.y;
    #pragma unroll
    for (int off = 32; off; off >>= 1) { s += __shfl_xor(s, off, 64); ss += __shfl_xor(ss, off, 64); }
    float mean = s * (1.0f/CDIM);
    float var  = ss * (1.0f/CDIM) - mean*mean;
    float rstd = rsqrtf(var + 1e-5f);
    int q = trans ? ((p % LDIM) * LDIM + p / LDIM) : p;
    ushort2 o;
    o.x = f2bf((v.x - mean) * rstd * w[lane<<1]     + b[lane<<1]);
    o.y = f2bf((v.y - mean) * rstd * w[(lane<<1)+1] + b[(lane<<1)+1]);
    *(ushort2*)(dst + (size_t)q * CDIM + (lane << 1)) = o;
}

// ------- fused proj GEMM + dual battn (verified r15 structure, M=128) -------
__global__ __launch_bounds__(256) void proj_battn_gemm(
    const ushort* __restrict__ A, const ushort* __restrict__ Wt, const float* __restrict__ pb,
    const float* __restrict__ rlnw, const float* __restrict__ rlnb, const float* __restrict__ rwb,
    const float* __restrict__ clnw, const float* __restrict__ clnb, const float* __restrict__ cwb,
    float* __restrict__ battn_r, float* __restrict__ battn_c)
{
    __shared__ ushort As[128*64];
    __shared__ ushort Ws[128*64];
    int t = threadIdx.x, l = t & 63, wv = t >> 6;
    int m0 = blockIdx.x << 7;
    int wm = (wv >> 1) << 6, wn = (wv & 1) << 6;
    int sr = t >> 1, sh = (t & 1) << 5;
    f32x4 acc[4][4] = {};
    for (int k0 = 0; k0 < 128; k0 += 64) {
        if (k0) __syncthreads();
        const ushort* ap = A + (size_t)(m0 + sr) * CDIM + k0 + sh;
        #pragma unroll
        for (int u = 0; u < 4; u++)
            *(int4*)((char*)As + swz128(sr, (sh << 1) + (u << 4))) = *(const int4*)(ap + (u << 3));
        const ushort* wp2 = Wt + (size_t)sr * CDIM + k0 + sh;
        #pragma unroll
        for (int u = 0; u < 4; u++)
            *(int4*)((char*)Ws + swz128(sr, (sh << 1) + (u << 4))) = *(const int4*)(wp2 + (u << 3));
        __syncthreads();
        #pragma unroll
        for (int ks = 0; ks < 2; ks++) {
            int kb = (ks << 6) + ((l >> 4) << 4);
            bf16x8 a[4], b[4];
            #pragma unroll
            for (int x = 0; x < 4; x++) {
                a[x] = *(const bf16x8*)((char*)As + swz128(wm + (x << 4) + (l & 15), kb));
                b[x] = *(const bf16x8*)((char*)Ws + swz128(wn + (x << 4) + (l & 15), kb));
            }
            #pragma unroll
            for (int i = 0; i < 4; i++)
            #pragma unroll
            for (int j = 0; j < 4; j++)
                acc[i][j] = __builtin_amdgcn_mfma_f32_16x16x32_bf16(a[i], b[j], acc[i][j], 0, 0, 0);
        }
    }
    int lc = l & 15, lr = l >> 4;
    float pbv[4], rlw[4], rlb[4], clw[4], clb[4];
    float4 rw4[4], cw4[4];
    #pragma unroll
    for (int nf = 0; nf < 4; nf++) {
        int col = wn + (nf << 4) + lc;
        pbv[nf] = pb[col];
        rlw[nf] = rlnw[col]; rlb[nf] = rlnb[col];
        clw[nf] = clnw[col]; clb[nf] = clnb[col];
        rw4[nf] = *(const float4*)&rwb[col * HN];
        cw4[nf] = *(const float4*)&cwb[col * HN];
    }
    float* buf  = (float*)Ws;
    float* dbuf = buf + 512;
    __syncthreads();
    #pragma unroll
    for (int mf = 0; mf < 4; mf++) {
        float v[4][4];
        #pragma unroll
        for (int r = 0; r < 4; r++)
        #pragma unroll
        for (int nf = 0; nf < 4; nf++)
            v[r][nf] = acc[mf][nf][r] + pbv[nf];
        float s[4], q[4];
        #pragma unroll
        for (int r = 0; r < 4; r++) {
            float a0 = 0.f, a1 = 0.f;
            #pragma unroll
            for (int nf = 0; nf < 4; nf++) { a0 += v[r][nf]; a1 += v[r][nf]*v[r][nf]; }
            s[r] = a0; q[r] = a1;
        }
        #pragma unroll
        for (int off = 1; off < 16; off <<= 1)
        #pragma unroll
        for (int r = 0; r < 4; r++) {
            s[r] += __shfl_xor(s[r], off, 64);
            q[r] += __shfl_xor(q[r], off, 64);
        }
        if (lc == 0) {
            #pragma unroll
            for (int r = 0; r < 4; r++) {
                int rl = wm + (mf << 4) + (lr << 2) + r;
                buf[(((wv & 1) << 7) + rl) * 2 + 0] = s[r];
                buf[(((wv & 1) << 7) + rl) * 2 + 1] = q[r];
            }
        }
        __syncthreads();
        float p[4][8];
        #pragma unroll
        for (int r = 0; r < 4; r++) {
            int rl = wm + (mf << 4) + (lr << 2) + r;
            float S = buf[rl * 2 + 0] + buf[(256 + rl * 2) + 0];
            float Q = buf[rl * 2 + 1] + buf[(256 + rl * 2) + 1];
            float mean = S * (1.f/CDIM);
            float var  = Q * (1.f/CDIM) - mean * mean;
            float rstd = rsqrtf(var + 1e-5f);
            float p0=0.f,p1=0.f,p2=0.f,p3=0.f,p4=0.f,p5=0.f,p6=0.f,p7=0.f;
            #pragma unroll
            for (int nf = 0; nf < 4; nf++) {
                float cn = (v[r][nf] - mean) * rstd;
                float xr = cn * rlw[nf] + rlb[nf];
                float xc = cn * clw[nf] + clb[nf];
                p0 += xr * rw4[nf].x; p1 += xr * rw4[nf].y;
                p2 += xr * rw4[nf].z; p3 += xr * rw4[nf].w;
                p4 += xc * cw4[nf].x; p5 += xc * cw4[nf].y;
                p6 += xc * cw4[nf].z; p7 += xc * cw4[nf].w;
            }
            p[r][0]=p0; p[r][1]=p1; p[r][2]=p2; p[r][3]=p3;
            p[r][4]=p4; p[r][5]=p5; p[r][6]=p6; p[r][7]=p7;
        }
        #pragma unroll
        for (int off = 1; off < 16; off <<= 1)
        #pragma unroll
        for (int r = 0; r < 4; r++)
        #pragma unroll
        for (int i = 0; i < 8; i++)
            p[r][i] += __shfl_xor(p[r][i], off, 64);
        if (wn == 0 && lc == 0) {
            #pragma unroll
            for (int r = 0; r < 4; r++) {
                int rl = wm + (mf << 4) + (lr << 2) + r;
                #pragma unroll
                for (int i = 0; i < 8; i++) dbuf[rl * 8 + i] = p[r][i];
            }
        }
        __syncthreads();
        if (wn == 64 && lc == 0) {
            #pragma unroll
            for (int r = 0; r < 4; r++) {
                int rl = wm + (mf << 4) + (lr << 2) + r;
                int rowg = m0 + rl;
                int a = rowg / LDIM, b2 = rowg % LDIM;
                #pragma unroll
                for (int h = 0; h < HN; h++) {
                    battn_r[((size_t)h*LDIM + b2)*LDIM + a]  = p[r][h]   + dbuf[rl*8 + h];
                    battn_c[((size_t)h*LDIM + a)*LDIM + b2]  = p[r][4+h] + dbuf[rl*8 + 4 + h];
                }
            }
        }
    }
}

// ------- M=64 retiled GEMM (verified r17 config). -------
template<int ACT, int AMODE, int OUTMODE, int LNOUT>
__global__ __launch_bounds__(256) void mgemm64(
    const void* __restrict__ Ain, const ushort* __restrict__ Wt,
    const float* __restrict__ bias, const ushort* __restrict__ gmul,
    const float* __restrict__ res, void* __restrict__ Cout,
    const float* __restrict__ lnw2, const float* __restrict__ lnb2, ushort* __restrict__ xln,
    int N, int KP, int lda, float alpha, int rtrans, int otrans)
{
    __shared__ ushort As[64*64];
    __shared__ ushort Ws[128*64];
    int t = threadIdx.x, l = t & 63, wv = t >> 6;
    int m0 = blockIdx.y << 6, n0 = blockIdx.x << 7;
    int wm = (wv >> 1) << 5;
    int wn = (wv & 1) << 6;
    int asr = t >> 2, ash = (t & 3) << 4;
    int wsr = t >> 1, wsh = (t & 1) << 5;
    f32x4 acc[2][4] = {};
    for (int k0 = 0; k0 < KP; k0 += 64) {
        if (k0) __syncthreads();
        if (AMODE == 1) {
            const ushort* ap = (const ushort*)Ain + (size_t)(m0 + asr) * lda + k0 + ash;
            *(int4*)((char*)As + swz128(asr, (ash << 1)))      = *(const int4*)ap;
            *(int4*)((char*)As + swz128(asr, (ash << 1) + 16)) = *(const int4*)(ap + 8);
        } else if (AMODE == 2) {
            const ushort* ap = (const ushort*)Ain + (size_t)(m0 + asr) * lda + k0 + ash;
            const ushort* gp = gmul + (size_t)(m0 + asr) * lda + k0 + ash;
            #pragma unroll
            for (int u = 0; u < 2; u++) {
                int4 av = *(const int4*)(ap + (u << 3));
                int4 gv = *(const int4*)(gp + (u << 3));
                ushort* au = (ushort*)&av; ushort* gu = (ushort*)&gv;
                short v8[8];
                #pragma unroll
                for (int e = 0; e < 8; e++) v8[e] = (short)f2bf(bf2f(au[e]) * bf2f(gu[e]));
                *(int4*)((char*)As + swz128(asr, (ash << 1) + (u << 4))) = *(int4*)v8;
            }
        } else {
            const float* ap = (const float*)Ain + (size_t)(m0 + asr) * lda;
            #pragma unroll
            for (int u = 0; u < 2; u++) {
                short v8[8];
                #pragma unroll
                for (int e = 0; e < 8; e++) {
                    int c = k0 + ash + (u << 3) + e;
                    v8[e] = (short)f2bf((c < lda) ? ap[c] : 0.f);
                }
                *(int4*)((char*)As + swz128(asr, (ash << 1) + (u << 4))) = *(int4*)v8;
            }
        }
        {
            const ushort* wp2 = Wt + (size_t)(n0 + wsr) * KP + k0 + wsh;
            #pragma unroll
            for (int u = 0; u < 4; u++)
                *(int4*)((char*)Ws + swz128(wsr, (wsh << 1) + (u << 4))) = *(const int4*)(wp2 + (u << 3));
        }
        __syncthreads();
        #pragma unroll
        for (int ks = 0; ks < 2; ks++) {
            int kb = (ks << 6) + ((l >> 4) << 4);
            bf16x8 a[2], b[4];
            #pragma unroll
            for (int x = 0; x < 2; x++)
                a[x] = *(const bf16x8*)((char*)As + swz128(wm + (x << 4) + (l & 15), kb));
            #pragma unroll
            for (int x = 0; x < 4; x++)
                b[x] = *(const bf16x8*)((char*)Ws + swz128(wn + (x << 4) + (l & 15), kb));
            #pragma unroll
            for (int i = 0; i < 2; i++)
            #pragma unroll
            for (int j = 0; j < 4; j++)
                acc[i][j] = __builtin_amdgcn_mfma_f32_16x16x32_bf16(a[i], b[j], acc[i][j], 0, 0, 0);
        }
    }
    if (LNOUT) {
        #pragma unroll
        for (int mf = 0; mf < 2; mf++)
        #pragma unroll
        for (int nf = 0; nf < 4; nf++) {
            int col  = wn + (nf << 4) + (l & 15);
            int row0 = m0 + wm + (mf << 4) + ((l >> 4) << 2);
            float bb = bias ? bias[col] : 0.f;
            #pragma unroll
            for (int r = 0; r < 4; r++) {
                int row = row0 + r;
                size_t rrow = rtrans ? trow(row) : (size_t)row;
                acc[mf][nf][r] = acc[mf][nf][r] * alpha + bb + (res ? res[rrow * CDIM + col] : 0.f);
            }
        }
        float ps[2][4], pq[2][4];
        #pragma unroll
        for (int mf = 0; mf < 2; mf++)
        #pragma unroll
        for (int r = 0; r < 4; r++) {
            float s = 0.f, q = 0.f;
            #pragma unroll
            for (int nf = 0; nf < 4; nf++) { float v = acc[mf][nf][r]; s += v; q += v * v; }
            ps[mf][r] = s; pq[mf][r] = q;
        }
        #pragma unroll
        for (int off = 1; off < 16; off <<= 1)
        #pragma unroll
        for (int mf = 0; mf < 2; mf++)
        #pragma unroll
        for (int r = 0; r < 4; r++) {
            ps[mf][r] += __shfl_xor(ps[mf][r], off, 64);
            pq[mf][r] += __shfl_xor(pq[mf][r], off, 64);
        }
        __syncthreads();
        float* lnbuf = (float*)As;
        if ((l & 15) == 0) {
            #pragma unroll
            for (int mf = 0; mf < 2; mf++)
            #pragma unroll
            for (int r = 0; r < 4; r++) {
                int rl = wm + (mf << 4) + ((l >> 4) << 2) + r;
                lnbuf[(((wv & 1) << 6) + rl) * 2 + 0] = ps[mf][r];
                lnbuf[(((wv & 1) << 6) + rl) * 2 + 1] = pq[mf][r];
            }
        }
        __syncthreads();
        #pragma unroll
        for (int mf = 0; mf < 2; mf++)
        #pragma unroll
        for (int nf = 0; nf < 4; nf++) {
            int col  = wn + (nf << 4) + (l & 15);
            int row0 = m0 + wm + (mf << 4) + ((l >> 4) << 2);
            float lw = lnw2[col], lb = lnb2[col];
            #pragma unroll
            for (int r = 0; r < 4; r++) {
                int row = row0 + r;
                int rl  = wm + (mf << 4) + ((l >> 4) << 2) + r;
                float s  = lnbuf[rl * 2 + 0] + lnbuf[(128 + rl * 2) + 0];
                float q  = lnbuf[rl * 2 + 1] + lnbuf[(128 + rl * 2) + 1];
                float mean = s * (1.f/CDIM);
                float var  = q * (1.f/CDIM) - mean * mean;
                float rstd = rsqrtf(var + 1e-5f);
                float o = acc[mf][nf][r];
                size_t orow = otrans ? trow(row) : (size_t)row;
                ((float*)Cout)[orow * CDIM + col] = o;
                xln[orow * CDIM + col] = f2bf((o - mean) * rstd * lw + lb);
            }
        }
    } else {
        #pragma unroll
        for (int mf = 0; mf < 2; mf++)
        #pragma unroll
        for (int nf = 0; nf < 4; nf++) {
            int col  = n0 + wn + (nf << 4) + (l & 15);
            int row0 = m0 + wm + (mf << 4) + ((l >> 4) << 2);
            float bb = bias ? bias[col] : 0.f;
            #pragma unroll
            for (int r = 0; r < 4; r++) {
                int row = row0 + r;
                float v = acc[mf][nf][r] * alpha + bb;
                if (ACT == 1) v = fmaxf(v, 0.f);
                if (ACT == 2) v = 1.f / (1.f + __expf(-v));
                if (OUTMODE == 0) {
                    float o = v + (res ? res[(size_t)row * N + col] : 0.f);
                    ((float*)Cout)[(size_t)row * N + col] = o;
                } else if (OUTMODE == 1) {
                    ((ushort*)Cout)[(size_t)row * N + col] = f2bf(v);
                } else {
                    size_t orow = otrans ? trow(row) : (size_t)row;
                    size_t rrow = rtrans ? trow(row) : (size_t)row;
                    float o = v + (res ? res[rrow * N + col] : 0.f);
                    ((float*)Cout)[orow * N + col] = o;
                }
            }
        }
    }
}

// ------- q,k,v,g: M=64 tile, Ws halved to [64][128] (16KB) -> 32KB total, 5 blocks/CU. -------
// Per comp, two n-halves; each wave computes 32x32 (acc[2][2]).
__global__ __launch_bounds__(256) void qkv4_gemm(
    const ushort* __restrict__ A, const ushort* __restrict__ wt4,
    ushort* __restrict__ qo, ushort* __restrict__ ko, ushort* __restrict__ vt,
    ushort* __restrict__ go, const float* __restrict__ bg,
    float scale_q, float scale_k)
{
    __shared__ ushort As[64*128];    // 16 KB
    __shared__ ushort Ws[64*128];    // 16 KB (64 out-cols of W)
    int t = threadIdx.x, l = t & 63, wv = t >> 6;
    int m0 = blockIdx.x << 6;
    int wm  = (wv >> 1) << 5;        // 0 / 32
    int wn2 = (wv & 1) << 5;         // 0 / 32
    int sr = t >> 2, scb = (t & 3) << 6;   // 4 threads/row, 64B each
    {
        const ushort* ap = A + (size_t)(m0 + sr) * CDIM + (scb >> 1);
        #pragma unroll
        for (int u = 0; u < 4; u++)
            *(int4*)((char*)As + swz256(sr, scb + (u << 4))) = *(const int4*)(ap + (u << 3));
    }
    for (int comp = 0; comp < 4; comp++) {
        #pragma unroll
        for (int nh = 0; nh < 2; nh++) {
            if (comp | nh) __syncthreads();
            {
                const ushort* wp2 = wt4 + (size_t)comp * 16384
                                  + (size_t)((nh << 6) + sr) * CDIM + (scb >> 1);
                #pragma unroll
                for (int u = 0; u < 4; u++)
                    *(int4*)((char*)Ws + swz256(sr, scb + (u << 4))) = *(const int4*)(wp2 + (u << 3));
            }
            __syncthreads();
            f32x4 acc[2][2] = {};
            #pragma unroll
            for (int ks = 0; ks < 4; ks++) {
                int kb = (ks << 6) + ((l >> 4) << 4);
                bf16x8 a[2], b[2];
                #pragma unroll
                for (int x = 0; x < 2; x++) {
                    a[x] = *(const bf16x8*)((char*)As + swz256(wm + (x << 4) + (l & 15), kb));
                    b[x] = *(const bf16x8*)((char*)Ws + swz256(wn2 + (x << 4) + (l & 15), kb));
                }
                #pragma unroll
                for (int i = 0; i < 2; i++)
                #pragma unroll
                for (int j = 0; j < 2; j++)
                    acc[i][j] = __builtin_amdgcn_mfma_f32_16x16x32_bf16(a[i], b[j], acc[i][j], 0, 0, 0);
            }
            #pragma unroll
            for (int mf = 0; mf < 2; mf++)
            #pragma unroll
            for (int nf = 0; nf < 2; nf++) {
                int col  = (nh << 6) + wn2 + (nf << 4) + (l & 15);
                int row0 = m0 + wm + (mf << 4) + ((l >> 4) << 2);
                if (comp == 0) {
                    #pragma unroll
                    for (int r = 0; r < 4; r++)
                        qo[(size_t)(row0 + r) * CDIM + col] = f2bf(acc[mf][nf][r] * scale_q);
                } else if (comp == 1) {
                    #pragma unroll
                    for (int r = 0; r < 4; r++)
                        ko[(size_t)(row0 + r) * CDIM + col] = f2bf(acc[mf][nf][r] * scale_k);
                } else if (comp == 2) {
                    ushort4 pk;
                    #pragma unroll
                    for (int r = 0; r < 4; r++) ((ushort*)&pk)[r] = f2bf(acc[mf][nf][r]);
                    int n = row0 / LDIM, j = row0 % LDIM;
                    *(ushort4*)&vt[((size_t)(col >> 5) * 12288 + (size_t)n * 32 + (col & 31)) * 384 + j] = pk;
                } else {
                    float bb = bg[col];
                    #pragma unroll
                    for (int r = 0; r < 4; r++) {
                        float v = acc[mf][nf][r] + bb;
                        go[(size_t)(row0 + r) * CDIM + col] = f2bf(1.f / (1.f + __expf(-v)));
                    }
                }
            }
        }
    }
}

// ------- tied scores (verified round-7 3D grid): partial[cz,h,i,j] -------
__global__ __launch_bounds__(256) void score128(const ushort* __restrict__ Q,
    const ushort* __restrict__ Kb, float* __restrict__ partial)
{
    __shared__ ushort As[128*128];
    __shared__ ushort Bs[128*128];
    int t = threadIdx.x, l = t & 63, wv = t >> 6;
    int ti = blockIdx.x / 3, tj = blockIdx.x % 3;
    int h = blockIdx.y, cz = blockIdx.z;
    int i0 = ti << 7, j0 = tj << 7;
    int wm = (wv >> 1) << 6, wn = (wv & 1) << 6;
    int sr = t >> 1, half = t & 1;
    f32x4 acc[4][4] = {};
    for (int it = 0; it < 12; it++) {
        if (it) __syncthreads();
        int nb = cz * 48 + (it << 2);
        #pragma unroll
        for (int e = 0; e < 2; e++) {
            int nq = (half << 1) + e;
            const ushort* qp = Q  + ((size_t)(nb + nq) * LDIM + i0 + sr) * CDIM + (h << 5);
            const ushort* kp = Kb + ((size_t)(nb + nq) * LDIM + j0 + sr) * CDIM + (h << 5);
            *(int4*)((char*)As + swz256(sr, (nq << 6) +  0)) = *(const int4*)qp;
            *(int4*)((char*)As + swz256(sr, (nq << 6) + 16)) = *(const int4*)(qp + 8);
            *(int4*)((char*)As + swz256(sr, (nq << 6) + 32)) = *(const int4*)(qp + 16);
            *(int4*)((char*)As + swz256(sr, (nq << 6) + 48)) = *(const int4*)(qp + 24);
            *(int4*)((char*)Bs + swz256(sr, (nq << 6) +  0)) = *(const int4*)kp;
            *(int4*)((char*)Bs + swz256(sr, (nq << 6) + 16)) = *(const int4*)(kp + 8);
            *(int4*)((char*)Bs + swz256(sr, (nq << 6) + 32)) = *(const int4*)(kp + 16);
            *(int4*)((char*)Bs + swz256(sr, (nq << 6) + 48)) = *(const int4*)(kp + 24);
        }
        __syncthreads();
        #pragma unroll
        for (int ks = 0; ks < 4; ks++) {
            int kb = (ks << 6) + ((l >> 4) << 4);
            bf16x8 a[4], b[4];
            #pragma unroll
            for (int x = 0; x < 4; x++) {
                a[x] = *(const bf16x8*)((char*)As + swz256(wm + (x << 4) + (l & 15), kb));
                b[x] = *(const bf16x8*)((char*)Bs + swz256(wn + (x << 4) + (l & 15), kb));
            }
            #pragma unroll
            for (int i = 0; i < 4; i++)
            #pragma unroll
            for (int j = 0; j < 4; j++)
                acc[i][j] = __builtin_amdgcn_mfma_f32_16x16x32_bf16(a[i], b[j], acc[i][j], 0, 0, 0);
        }
    }
    #pragma unroll
    for (int mf = 0; mf < 4; mf++)
    #pragma unroll
    for (int nf = 0; nf < 4; nf++) {
        int j = j0 + wn + (nf << 4) + (l & 15);
        int i = i0 + wm + (mf << 4) + ((l >> 4) << 2);
        #pragma unroll
        for (int r = 0; r < 4; r++)
            partial[((size_t)(cz*HN + h)*LDIM + i + r)*LDIM + j] = acc[mf][nf][r];
    }
}

// ---------------- softmax over j (chunk reduce + bias) -> bf16 ----------------
__global__ __launch_bounds__(64) void softmax_kernel(
    const float* __restrict__ partial, const float* __restrict__ battn, ushort* __restrict__ attn)
{
    int hi = blockIdx.x;
    int l = threadIdx.x;
    float s[6];
    #pragma unroll
    for (int u = 0; u < 6; u++) {
        size_t idx = (size_t)hi * LDIM + l + (u << 6);
        float v = battn[idx];
        #pragma unroll
        for (int c = 0; c < NCHUNK; c++) v += partial[(size_t)c * HN * LL + idx];
        s[u] = v;
    }
    float m = s[0];
    #pragma unroll
    for (int u = 1; u < 6; u++) m = fmaxf(m, s[u]);
    #pragma unroll
    for (int off = 32; off; off >>= 1) m = fmaxf(m, __shfl_xor(m, off, 64));
    float sum = 0.f;
    #pragma unroll
    for (int u = 0; u < 6; u++) { s[u] = __expf(s[u] - m); sum += s[u]; }
    #pragma unroll
    for (int off = 32; off; off >>= 1) sum += __shfl_xor(sum, off, 64);
    float inv = 1.f / sum;
    #pragma unroll
    for (int u = 0; u < 6; u++) attn[(size_t)hi * LDIM + l + (u << 6)] = f2bf(s[u] * inv);
}

// ------- PV per-head GEMM (BK=64): pvout[(n,i),h*32+d] -------
__global__ __launch_bounds__(256) void pvg_gemm(const ushort* __restrict__ attn,
    const ushort* __restrict__ vt, ushort* __restrict__ pvout)
{
    __shared__ ushort As[128*64];
    __shared__ ushort Ws[128*64];
    int t = threadIdx.x, l = t & 63, wv = t >> 6;
    int n0 = blockIdx.x << 7;
    int i0 = blockIdx.y << 7;
    int h  = blockIdx.z;
    const ushort* abase = attn + (size_t)h * LL;
    const ushort* bbase = vt + (size_t)h * VTPLANE;
    int wm = (wv >> 1) << 6, wn = (wv & 1) << 6;
    int sr = t >> 1, sh = (t & 1) << 5;
    f32x4 acc[4][4] = {};
    for (int k0 = 0; k0 < LDIM; k0 += 64) {
        if (k0) __syncthreads();
        {
            const ushort* ap = abase + (size_t)(i0 + sr) * LDIM + k0 + sh;
            const ushort* bp = bbase + (size_t)(n0 + sr) * LDIM + k0 + sh;
            #pragma unroll
            for (int u = 0; u < 4; u++) {
                *(int4*)((char*)As + swz128(sr, (sh << 1) + (u << 4))) = *(const int4*)(ap + (u << 3));
                *(int4*)((char*)Ws + swz128(sr, (sh << 1) + (u << 4))) = *(const int4*)(bp + (u << 3));
            }
        }
        __syncthreads();
        #pragma unroll
        for (int ks = 0; ks < 2; ks++) {
            int kb = (ks << 6) + ((l >> 4) << 4);
            bf16x8 a[4], b[4];
            #pragma unroll
            for (int x = 0; x < 4; x++) {
                a[x] = *(const bf16x8*)((char*)As + swz128(wm + (x << 4) + (l & 15), kb));
                b[x] = *(const bf16x8*)((char*)Ws + swz128(wn + (x << 4) + (l & 15), kb));
            }
            #pragma unroll
            for (int i = 0; i < 4; i++)
            #pragma unroll
            for (int j = 0; j < 4; j++)
                acc[i][j] = __builtin_amdgcn_mfma_f32_16x16x32_bf16(a[i], b[j], acc[i][j], 0, 0, 0);
        }
    }
    #pragma unroll
    for (int mf = 0; mf < 4; mf++)
    #pragma unroll
    for (int nf = 0; nf < 4; nf++) {
        int col  = n0 + wn + (nf << 4) + (l & 15);
        int row0 = i0 + wm + (mf << 4) + ((l >> 4) << 2);
        int n = col >> 5, d = col & 31;
        #pragma unroll
        for (int r = 0; r < 4; r++) {
            int i = row0 + r;
            pvout[((size_t)n * LDIM + i) * CDIM + (h << 5) + d] = f2bf(acc[mf][nf][r]);
        }
    }
}

extern "C" void kernel_launch(void* const* d_in, const int* in_sizes, int n_in,
                              void* d_out, int out_size, void* d_ws, size_t ws_size,
                              hipStream_t stream)
{
    const float* pair     = (const float*)d_in[0];
    const float* rbf_feat = (const float*)d_in[1];
    const float* emb_b    = (const float*)d_in[3];
    const float* proj_b   = (const float*)d_in[5];
    const float* ff_ln_w  = (const float*)d_in[30];
    const float* ff_ln_b  = (const float*)d_in[31];
    const float* ff_b1    = (const float*)d_in[33];
    const float* ff_b2    = (const float*)d_in[35];
    float* out = (float*)d_out;

    ushort* R0 = (ushort*)d_ws;
    ushort* R1 = R0 + (size_t)LL*CDIM;
    ushort* R2 = R1 + (size_t)LL*CDIM;
    ushort* R3 = R2 + (size_t)LL*CDIM;
    float*  partialb = (float*)(R3 + (size_t)LL*CDIM);
    float*  battn_r  = partialb + (size_t)NCHUNK*HN*LL;
    float*  battn_c  = battn_r  + (size_t)HN*LL;
    ushort* attn_bf  = (ushort*)(battn_c + (size_t)HN*LL);
    ushort* wt       = attn_bf + (size_t)HN*LL;

    size_t need_bytes = (size_t)4*LL*CDIM*2 + ((size_t)NCHUNK*HN*LL + 2*(size_t)HN*LL)*4
                      + (size_t)HN*LL*2 + (size_t)262144*2;
    if (ws_size < need_bytes) return;

    const size_t WS = 16384;
    ushort* wt_emb  = wt;
    ushort* wt_proj = wt + WS;
    ushort* wt_ff1  = wt + 12*WS;
    ushort* wt_ff2  = wt + 12*WS + 32768;

    const float SCALE = 0.17677669529663687f;  // 32^-0.5

    wprep_kernel<<<dim3(128, 14), 256, 0, stream>>>(wt,
        (const float*)d_in[2], (const float*)d_in[4],
        (const float*)d_in[10], (const float*)d_in[11], (const float*)d_in[12],
        (const float*)d_in[14], (const float*)d_in[16],
        (const float*)d_in[22], (const float*)d_in[23], (const float*)d_in[24],
        (const float*)d_in[26], (const float*)d_in[28],
        (const float*)d_in[32], (const float*)d_in[34]);

    // emb hidden bf16 -> R3
    mgemm64<1,0,1,0><<<dim3(1,LL/64), 256, 0, stream>>>(rbf_feat, wt_emb, emb_b, nullptr, nullptr, R3,
        nullptr, nullptr, nullptr, 128, 128, 36, 1.f, 0, 0);
    // fused proj + dual battn: rbf never materialized
    proj_battn_gemm<<<1152, 256, 0, stream>>>(R3, wt_proj, proj_b,
        (const float*)d_in[8],  (const float*)d_in[9],  (const float*)d_in[13],
        (const float*)d_in[20], (const float*)d_in[21], (const float*)d_in[25],
        battn_r, battn_c);

    // initial row-pass xln (transposed frame) -> R3
    lnpack_kernel<<<LL/4, 256, 0, stream>>>(pair, R3, (const float*)d_in[6], (const float*)d_in[7], 1);

    ushort* XLN = R3;
    for (int pass = 0; pass < 2; pass++) {
        const float* const* wp = (const float* const*)(d_in + (pass ? 18 : 6));
        int trans = pass ? 0 : 1;
        const float* P = pass ? (const float*)out : pair;
        const float* battnb = pass ? battn_c : battn_r;
        int ws0 = pass ? 7 : 2;
        const float* nlw = pass ? ff_ln_w : (const float*)d_in[18];
        const float* nlb = pass ? ff_ln_b : (const float*)d_in[19];
        ushort* Qb   = R0;
        ushort* Kb2  = pass ? R3 : R1;
        ushort* VTb  = R2;
        ushort* PVb  = R0;
        ushort* XLNn = pass ? R3 : R1;
        qkv4_gemm<<<LL/64, 256, 0, stream>>>(XLN, wt + ws0*WS, Qb, Kb2, VTb, XLN, wp[9], SCALE, 1.f/LDIM);
        score128<<<dim3(9, HN, NCHUNK), 256, 0, stream>>>(Qb, Kb2, partialb);
        softmax_kernel<<<HN*LDIM, 64, 0, stream>>>(partialb, battnb, attn_bf);
        pvg_gemm<<<dim3(96, 3, 4), 256, 0, stream>>>(attn_bf, VTb, PVb);
        mgemm64<0,2,3,1><<<dim3(1,LL/64), 256, 0, stream>>>(PVb, wt + (ws0+4)*WS, wp[11], XLN, P, out,
            nlw, nlb, XLNn, 128, 128, 128, 1.f, trans, trans);
        XLN = XLNn;
    }

    // FFN: out += relu(xln@w1+b1)@w2+b2  (h1 bf16 [LL][256] spans R0+R1)
    mgemm64<1,1,1,0><<<dim3(2,LL/64), 256, 0, stream>>>(XLN, wt_ff1, ff_b1, nullptr, nullptr, R0,
        nullptr, nullptr, nullptr, 256, 128, 128, 1.f, 0, 0);
    mgemm64<0,1,0,0><<<dim3(1,LL/64), 256, 0, stream>>>(R0, wt_ff2, ff_b2, nullptr, out, out,
        nullptr, nullptr, nullptr, 128, 256, 256, 1.f, 0, 0);
}

// Round 19
// 650.325 us; speedup vs baseline: 1.1699x; 1.0648x over previous
//
#include <hip/hip_runtime.h>
#include <hip/hip_bf16.h>
#include <math.h>

#define LDIM 384
#define CDIM 128
#define HN 4
#define LL (LDIM*LDIM)
#define NCHUNK 8
#define VTPLANE ((size_t)12288*384)

typedef __attribute__((ext_vector_type(8))) short bf16x8;
typedef __attribute__((ext_vector_type(4))) float f32x4;

__device__ __forceinline__ ushort f2bf(float x) {
    union { __hip_bfloat16 h; ushort u; } cv;
    cv.h = __float2bfloat16(x);
    return cv.u;
}
__device__ __forceinline__ float bf2f(ushort u) {
    union { unsigned int i; float f; } cv; cv.i = ((unsigned int)u) << 16; return cv.f;
}
__device__ __forceinline__ int swz256(int row, int cb) {
    return (row * 256 + cb) ^ ((row & 7) << 4) ^ ((cb & 128) >> 3);
}
__device__ __forceinline__ int swz128(int row, int cb) { return (row * 128 + cb) ^ ((row & 7) << 4); }
__device__ __forceinline__ size_t trow(int row) { return (size_t)(row % LDIM) * LDIM + row / LDIM; }

// ---------------- weight prep: fp32 [K][N] -> bf16 [N][KP] (zero-padded K) ----------------
__global__ __launch_bounds__(256) void wprep_kernel(ushort* __restrict__ wt,
    const float* emb_w, const float* proj_w,
    const float* rwq, const float* rwk, const float* rwv, const float* rwg, const float* rwo,
    const float* cwq, const float* cwk, const float* cwv, const float* cwg, const float* cwo,
    const float* ffw1, const float* ffw2)
{
    int y = blockIdx.y;
    const float* src; int N, K, KP; size_t off;
    switch (y) {
        case 0:  src = emb_w;  N = 128; K = 36;  KP = 128; off = 0;         break;
        case 1:  src = proj_w; N = 128; K = 128; KP = 128; off = 16384;     break;
        case 2:  src = rwq;    N = 128; K = 128; KP = 128; off = 2*16384;   break;
        case 3:  src = rwk;    N = 128; K = 128; KP = 128; off = 3*16384;   break;
        case 4:  src = rwv;    N = 128; K = 128; KP = 128; off = 4*16384;   break;
        case 5:  src = rwg;    N = 128; K = 128; KP = 128; off = 5*16384;   break;
        case 6:  src = rwo;    N = 128; K = 128; KP = 128; off = 6*16384;   break;
        case 7:  src = cwq;    N = 128; K = 128; KP = 128; off = 7*16384;   break;
        case 8:  src = cwk;    N = 128; K = 128; KP = 128; off = 8*16384;   break;
        case 9:  src = cwv;    N = 128; K = 128; KP = 128; off = 9*16384;   break;
        case 10: src = cwg;    N = 128; K = 128; KP = 128; off = 10*16384;  break;
        case 11: src = cwo;    N = 128; K = 128; KP = 128; off = 11*16384;  break;
        case 12: src = ffw1;   N = 256; K = 128; KP = 128; off = 12*16384;  break;
        default: src = ffw2;   N = 128; K = 256; KP = 256; off = 12*16384 + 32768; break;
    }
    int e = blockIdx.x * 256 + threadIdx.x;
    if (e >= N * KP) return;
    int nn = e / KP, kp = e - nn * KP;
    float v = (kp < K) ? src[(size_t)kp * N + nn] : 0.f;
    wt[off + e] = f2bf(v);
}

// ------- LN + bf16 pack: coalesced read of src row p, write to dst row trans(p) -------
__global__ __launch_bounds__(256) void lnpack_kernel(const float* __restrict__ src,
    ushort* __restrict__ dst, const float* __restrict__ w, const float* __restrict__ b, int trans)
{
    int p = (blockIdx.x << 2) + (threadIdx.x >> 6);
    int lane = threadIdx.x & 63;
    float2 v = *(const float2*)(src + (size_t)p * CDIM + (lane << 1));
    float s  = v.x + v.y;
    float ss = v.x*v.x + v.y*v.y;
    #pragma unroll
    for (int off = 32; off; off >>= 1) { s += __shfl_xor(s, off, 64); ss += __shfl_xor(ss, off, 64); }
    float mean = s * (1.0f/CDIM);
    float var  = ss * (1.0f/CDIM) - mean*mean;
    float rstd = rsqrtf(var + 1e-5f);
    int q = trans ? ((p % LDIM) * LDIM + p / LDIM) : p;
    ushort2 o;
    o.x = f2bf((v.x - mean) * rstd * w[lane<<1]     + b[lane<<1]);
    o.y = f2bf((v.y - mean) * rstd * w[(lane<<1)+1] + b[(lane<<1)+1]);
    *(ushort2*)(dst + (size_t)q * CDIM + (lane << 1)) = o;
}

// ------- fused proj GEMM + dual battn (verified r15 structure, M=128) -------
__global__ __launch_bounds__(256) void proj_battn_gemm(
    const ushort* __restrict__ A, const ushort* __restrict__ Wt, const float* __restrict__ pb,
    const float* __restrict__ rlnw, const float* __restrict__ rlnb, const float* __restrict__ rwb,
    const float* __restrict__ clnw, const float* __restrict__ clnb, const float* __restrict__ cwb,
    float* __restrict__ battn_r, float* __restrict__ battn_c)
{
    __shared__ ushort As[128*64];
    __shared__ ushort Ws[128*64];
    int t = threadIdx.x, l = t & 63, wv = t >> 6;
    int m0 = blockIdx.x << 7;
    int wm = (wv >> 1) << 6, wn = (wv & 1) << 6;
    int sr = t >> 1, sh = (t & 1) << 5;
    f32x4 acc[4][4] = {};
    for (int k0 = 0; k0 < 128; k0 += 64) {
        if (k0) __syncthreads();
        const ushort* ap = A + (size_t)(m0 + sr) * CDIM + k0 + sh;
        #pragma unroll
        for (int u = 0; u < 4; u++)
            *(int4*)((char*)As + swz128(sr, (sh << 1) + (u << 4))) = *(const int4*)(ap + (u << 3));
        const ushort* wp2 = Wt + (size_t)sr * CDIM + k0 + sh;
        #pragma unroll
        for (int u = 0; u < 4; u++)
            *(int4*)((char*)Ws + swz128(sr, (sh << 1) + (u << 4))) = *(const int4*)(wp2 + (u << 3));
        __syncthreads();
        #pragma unroll
        for (int ks = 0; ks < 2; ks++) {
            int kb = (ks << 6) + ((l >> 4) << 4);
            bf16x8 a[4], b[4];
            #pragma unroll
            for (int x = 0; x < 4; x++) {
                a[x] = *(const bf16x8*)((char*)As + swz128(wm + (x << 4) + (l & 15), kb));
                b[x] = *(const bf16x8*)((char*)Ws + swz128(wn + (x << 4) + (l & 15), kb));
            }
            #pragma unroll
            for (int i = 0; i < 4; i++)
            #pragma unroll
            for (int j = 0; j < 4; j++)
                acc[i][j] = __builtin_amdgcn_mfma_f32_16x16x32_bf16(a[i], b[j], acc[i][j], 0, 0, 0);
        }
    }
    int lc = l & 15, lr = l >> 4;
    float pbv[4], rlw[4], rlb[4], clw[4], clb[4];
    float4 rw4[4], cw4[4];
    #pragma unroll
    for (int nf = 0; nf < 4; nf++) {
        int col = wn + (nf << 4) + lc;
        pbv[nf] = pb[col];
        rlw[nf] = rlnw[col]; rlb[nf] = rlnb[col];
        clw[nf] = clnw[col]; clb[nf] = clnb[col];
        rw4[nf] = *(const float4*)&rwb[col * HN];
        cw4[nf] = *(const float4*)&cwb[col * HN];
    }
    float* buf  = (float*)Ws;
    float* dbuf = buf + 512;
    __syncthreads();
    #pragma unroll
    for (int mf = 0; mf < 4; mf++) {
        float v[4][4];
        #pragma unroll
        for (int r = 0; r < 4; r++)
        #pragma unroll
        for (int nf = 0; nf < 4; nf++)
            v[r][nf] = acc[mf][nf][r] + pbv[nf];
        float s[4], q[4];
        #pragma unroll
        for (int r = 0; r < 4; r++) {
            float a0 = 0.f, a1 = 0.f;
            #pragma unroll
            for (int nf = 0; nf < 4; nf++) { a0 += v[r][nf]; a1 += v[r][nf]*v[r][nf]; }
            s[r] = a0; q[r] = a1;
        }
        #pragma unroll
        for (int off = 1; off < 16; off <<= 1)
        #pragma unroll
        for (int r = 0; r < 4; r++) {
            s[r] += __shfl_xor(s[r], off, 64);
            q[r] += __shfl_xor(q[r], off, 64);
        }
        if (lc == 0) {
            #pragma unroll
            for (int r = 0; r < 4; r++) {
                int rl = wm + (mf << 4) + (lr << 2) + r;
                buf[(((wv & 1) << 7) + rl) * 2 + 0] = s[r];
                buf[(((wv & 1) << 7) + rl) * 2 + 1] = q[r];
            }
        }
        __syncthreads();
        float p[4][8];
        #pragma unroll
        for (int r = 0; r < 4; r++) {
            int rl = wm + (mf << 4) + (lr << 2) + r;
            float S = buf[rl * 2 + 0] + buf[(256 + rl * 2) + 0];
            float Q = buf[rl * 2 + 1] + buf[(256 + rl * 2) + 1];
            float mean = S * (1.f/CDIM);
            float var  = Q * (1.f/CDIM) - mean * mean;
            float rstd = rsqrtf(var + 1e-5f);
            float p0=0.f,p1=0.f,p2=0.f,p3=0.f,p4=0.f,p5=0.f,p6=0.f,p7=0.f;
            #pragma unroll
            for (int nf = 0; nf < 4; nf++) {
                float cn = (v[r][nf] - mean) * rstd;
                float xr = cn * rlw[nf] + rlb[nf];
                float xc = cn * clw[nf] + clb[nf];
                p0 += xr * rw4[nf].x; p1 += xr * rw4[nf].y;
                p2 += xr * rw4[nf].z; p3 += xr * rw4[nf].w;
                p4 += xc * cw4[nf].x; p5 += xc * cw4[nf].y;
                p6 += xc * cw4[nf].z; p7 += xc * cw4[nf].w;
            }
            p[r][0]=p0; p[r][1]=p1; p[r][2]=p2; p[r][3]=p3;
            p[r][4]=p4; p[r][5]=p5; p[r][6]=p6; p[r][7]=p7;
        }
        #pragma unroll
        for (int off = 1; off < 16; off <<= 1)
        #pragma unroll
        for (int r = 0; r < 4; r++)
        #pragma unroll
        for (int i = 0; i < 8; i++)
            p[r][i] += __shfl_xor(p[r][i], off, 64);
        if (wn == 0 && lc == 0) {
            #pragma unroll
            for (int r = 0; r < 4; r++) {
                int rl = wm + (mf << 4) + (lr << 2) + r;
                #pragma unroll
                for (int i = 0; i < 8; i++) dbuf[rl * 8 + i] = p[r][i];
            }
        }
        __syncthreads();
        if (wn == 64 && lc == 0) {
            #pragma unroll
            for (int r = 0; r < 4; r++) {
                int rl = wm + (mf << 4) + (lr << 2) + r;
                int rowg = m0 + rl;
                int a = rowg / LDIM, b2 = rowg % LDIM;
                #pragma unroll
                for (int h = 0; h < HN; h++) {
                    battn_r[((size_t)h*LDIM + b2)*LDIM + a]  = p[r][h]   + dbuf[rl*8 + h];
                    battn_c[((size_t)h*LDIM + a)*LDIM + b2]  = p[r][4+h] + dbuf[rl*8 + 4 + h];
                }
            }
        }
    }
}

// ------- M=64 retiled GEMM (verified r17 config). -------
template<int ACT, int AMODE, int OUTMODE, int LNOUT>
__global__ __launch_bounds__(256) void mgemm64(
    const void* __restrict__ Ain, const ushort* __restrict__ Wt,
    const float* __restrict__ bias, const ushort* __restrict__ gmul,
    const float* __restrict__ res, void* __restrict__ Cout,
    const float* __restrict__ lnw2, const float* __restrict__ lnb2, ushort* __restrict__ xln,
    int N, int KP, int lda, float alpha, int rtrans, int otrans)
{
    __shared__ ushort As[64*64];
    __shared__ ushort Ws[128*64];
    int t = threadIdx.x, l = t & 63, wv = t >> 6;
    int m0 = blockIdx.y << 6, n0 = blockIdx.x << 7;
    int wm = (wv >> 1) << 5;
    int wn = (wv & 1) << 6;
    int asr = t >> 2, ash = (t & 3) << 4;
    int wsr = t >> 1, wsh = (t & 1) << 5;
    f32x4 acc[2][4] = {};
    for (int k0 = 0; k0 < KP; k0 += 64) {
        if (k0) __syncthreads();
        if (AMODE == 1) {
            const ushort* ap = (const ushort*)Ain + (size_t)(m0 + asr) * lda + k0 + ash;
            *(int4*)((char*)As + swz128(asr, (ash << 1)))      = *(const int4*)ap;
            *(int4*)((char*)As + swz128(asr, (ash << 1) + 16)) = *(const int4*)(ap + 8);
        } else if (AMODE == 2) {
            const ushort* ap = (const ushort*)Ain + (size_t)(m0 + asr) * lda + k0 + ash;
            const ushort* gp = gmul + (size_t)(m0 + asr) * lda + k0 + ash;
            #pragma unroll
            for (int u = 0; u < 2; u++) {
                int4 av = *(const int4*)(ap + (u << 3));
                int4 gv = *(const int4*)(gp + (u << 3));
                ushort* au = (ushort*)&av; ushort* gu = (ushort*)&gv;
                short v8[8];
                #pragma unroll
                for (int e = 0; e < 8; e++) v8[e] = (short)f2bf(bf2f(au[e]) * bf2f(gu[e]));
                *(int4*)((char*)As + swz128(asr, (ash << 1) + (u << 4))) = *(int4*)v8;
            }
        } else {
            const float* ap = (const float*)Ain + (size_t)(m0 + asr) * lda;
            #pragma unroll
            for (int u = 0; u < 2; u++) {
                short v8[8];
                #pragma unroll
                for (int e = 0; e < 8; e++) {
                    int c = k0 + ash + (u << 3) + e;
                    v8[e] = (short)f2bf((c < lda) ? ap[c] : 0.f);
                }
                *(int4*)((char*)As + swz128(asr, (ash << 1) + (u << 4))) = *(int4*)v8;
            }
        }
        {
            const ushort* wp2 = Wt + (size_t)(n0 + wsr) * KP + k0 + wsh;
            #pragma unroll
            for (int u = 0; u < 4; u++)
                *(int4*)((char*)Ws + swz128(wsr, (wsh << 1) + (u << 4))) = *(const int4*)(wp2 + (u << 3));
        }
        __syncthreads();
        #pragma unroll
        for (int ks = 0; ks < 2; ks++) {
            int kb = (ks << 6) + ((l >> 4) << 4);
            bf16x8 a[2], b[4];
            #pragma unroll
            for (int x = 0; x < 2; x++)
                a[x] = *(const bf16x8*)((char*)As + swz128(wm + (x << 4) + (l & 15), kb));
            #pragma unroll
            for (int x = 0; x < 4; x++)
                b[x] = *(const bf16x8*)((char*)Ws + swz128(wn + (x << 4) + (l & 15), kb));
            #pragma unroll
            for (int i = 0; i < 2; i++)
            #pragma unroll
            for (int j = 0; j < 4; j++)
                acc[i][j] = __builtin_amdgcn_mfma_f32_16x16x32_bf16(a[i], b[j], acc[i][j], 0, 0, 0);
        }
    }
    if (LNOUT) {
        #pragma unroll
        for (int mf = 0; mf < 2; mf++)
        #pragma unroll
        for (int nf = 0; nf < 4; nf++) {
            int col  = wn + (nf << 4) + (l & 15);
            int row0 = m0 + wm + (mf << 4) + ((l >> 4) << 2);
            float bb = bias ? bias[col] : 0.f;
            #pragma unroll
            for (int r = 0; r < 4; r++) {
                int row = row0 + r;
                size_t rrow = rtrans ? trow(row) : (size_t)row;
                acc[mf][nf][r] = acc[mf][nf][r] * alpha + bb + (res ? res[rrow * CDIM + col] : 0.f);
            }
        }
        float ps[2][4], pq[2][4];
        #pragma unroll
        for (int mf = 0; mf < 2; mf++)
        #pragma unroll
        for (int r = 0; r < 4; r++) {
            float s = 0.f, q = 0.f;
            #pragma unroll
            for (int nf = 0; nf < 4; nf++) { float v = acc[mf][nf][r]; s += v; q += v * v; }
            ps[mf][r] = s; pq[mf][r] = q;
        }
        #pragma unroll
        for (int off = 1; off < 16; off <<= 1)
        #pragma unroll
        for (int mf = 0; mf < 2; mf++)
        #pragma unroll
        for (int r = 0; r < 4; r++) {
            ps[mf][r] += __shfl_xor(ps[mf][r], off, 64);
            pq[mf][r] += __shfl_xor(pq[mf][r], off, 64);
        }
        __syncthreads();
        float* lnbuf = (float*)As;
        if ((l & 15) == 0) {
            #pragma unroll
            for (int mf = 0; mf < 2; mf++)
            #pragma unroll
            for (int r = 0; r < 4; r++) {
                int rl = wm + (mf << 4) + ((l >> 4) << 2) + r;
                lnbuf[(((wv & 1) << 6) + rl) * 2 + 0] = ps[mf][r];
                lnbuf[(((wv & 1) << 6) + rl) * 2 + 1] = pq[mf][r];
            }
        }
        __syncthreads();
        #pragma unroll
        for (int mf = 0; mf < 2; mf++)
        #pragma unroll
        for (int nf = 0; nf < 4; nf++) {
            int col  = wn + (nf << 4) + (l & 15);
            int row0 = m0 + wm + (mf << 4) + ((l >> 4) << 2);
            float lw = lnw2[col], lb = lnb2[col];
            #pragma unroll
            for (int r = 0; r < 4; r++) {
                int row = row0 + r;
                int rl  = wm + (mf << 4) + ((l >> 4) << 2) + r;
                float s  = lnbuf[rl * 2 + 0] + lnbuf[(128 + rl * 2) + 0];
                float q  = lnbuf[rl * 2 + 1] + lnbuf[(128 + rl * 2) + 1];
                float mean = s * (1.f/CDIM);
                float var  = q * (1.f/CDIM) - mean * mean;
                float rstd = rsqrtf(var + 1e-5f);
                float o = acc[mf][nf][r];
                size_t orow = otrans ? trow(row) : (size_t)row;
                ((float*)Cout)[orow * CDIM + col] = o;
                xln[orow * CDIM + col] = f2bf((o - mean) * rstd * lw + lb);
            }
        }
    } else {
        #pragma unroll
        for (int mf = 0; mf < 2; mf++)
        #pragma unroll
        for (int nf = 0; nf < 4; nf++) {
            int col  = n0 + wn + (nf << 4) + (l & 15);
            int row0 = m0 + wm + (mf << 4) + ((l >> 4) << 2);
            float bb = bias ? bias[col] : 0.f;
            #pragma unroll
            for (int r = 0; r < 4; r++) {
                int row = row0 + r;
                float v = acc[mf][nf][r] * alpha + bb;
                if (ACT == 1) v = fmaxf(v, 0.f);
                if (ACT == 2) v = 1.f / (1.f + __expf(-v));
                if (OUTMODE == 0) {
                    float o = v + (res ? res[(size_t)row * N + col] : 0.f);
                    ((float*)Cout)[(size_t)row * N + col] = o;
                } else if (OUTMODE == 1) {
                    ((ushort*)Cout)[(size_t)row * N + col] = f2bf(v);
                } else {
                    size_t orow = otrans ? trow(row) : (size_t)row;
                    size_t rrow = rtrans ? trow(row) : (size_t)row;
                    float o = v + (res ? res[rrow * N + col] : 0.f);
                    ((float*)Cout)[orow * N + col] = o;
                }
            }
        }
    }
}

// ------- q,k,v,g: M=64 tile, Ws [64][128]; coalesced epilogue via LDS transpose. -------
// Per (comp, nh): MFMA -> sync -> acc->Tb (bf16, padded stride 72) -> sync -> 32B/thread stores.
__global__ __launch_bounds__(256) void qkv4_gemm(
    const ushort* __restrict__ A, const ushort* __restrict__ wt4,
    ushort* __restrict__ qo, ushort* __restrict__ ko, ushort* __restrict__ vt,
    ushort* __restrict__ go, const float* __restrict__ bg,
    float scale_q, float scale_k)
{
    __shared__ ushort As[64*128];    // 16 KB
    __shared__ ushort Ws[64*128];    // 16 KB (64 out-cols of W; reused as transpose buf)
    int t = threadIdx.x, l = t & 63, wv = t >> 6;
    int m0 = blockIdx.x << 6;
    int wm  = (wv >> 1) << 5;        // 0 / 32
    int wn2 = (wv & 1) << 5;         // 0 / 32
    int lc = l & 15, lr = l >> 4;
    int sr = t >> 2, scb = (t & 3) << 6;
    int n_blk = m0 / LDIM, jb = m0 % LDIM;   // 64-row tile never crosses n
    {
        const ushort* ap = A + (size_t)(m0 + sr) * CDIM + (scb >> 1);
        #pragma unroll
        for (int u = 0; u < 4; u++)
            *(int4*)((char*)As + swz256(sr, scb + (u << 4))) = *(const int4*)(ap + (u << 3));
    }
    ushort* Tb = Ws;                 // transpose buffer, [64][72] shorts
    int orow = t >> 2, oc = (t & 3) << 4;   // epilogue copy: 4 thr/row, 16 shorts each
    for (int comp = 0; comp < 4; comp++) {
        #pragma unroll
        for (int nh = 0; nh < 2; nh++) {
            if (comp | nh) __syncthreads();
            {
                const ushort* wp2 = wt4 + (size_t)comp * 16384
                                  + (size_t)((nh << 6) + sr) * CDIM + (scb >> 1);
                #pragma unroll
                for (int u = 0; u < 4; u++)
                    *(int4*)((char*)Ws + swz256(sr, scb + (u << 4))) = *(const int4*)(wp2 + (u << 3));
            }
            __syncthreads();
            f32x4 acc[2][2] = {};
            #pragma unroll
            for (int ks = 0; ks < 4; ks++) {
                int kb = (ks << 6) + ((l >> 4) << 4);
                bf16x8 a[2], b[2];
                #pragma unroll
                for (int x = 0; x < 2; x++) {
                    a[x] = *(const bf16x8*)((char*)As + swz256(wm + (x << 4) + (l & 15), kb));
                    b[x] = *(const bf16x8*)((char*)Ws + swz256(wn2 + (x << 4) + (l & 15), kb));
                }
                #pragma unroll
                for (int i = 0; i < 2; i++)
                #pragma unroll
                for (int j = 0; j < 2; j++)
                    acc[i][j] = __builtin_amdgcn_mfma_f32_16x16x32_bf16(a[i], b[j], acc[i][j], 0, 0, 0);
            }
            __syncthreads();   // all waves done reading Ws -> reuse as Tb
            #pragma unroll
            for (int mf = 0; mf < 2; mf++)
            #pragma unroll
            for (int nf = 0; nf < 2; nf++) {
                int cl = wn2 + (nf << 4) + lc;          // 0..63 (col within nh-half)
                int rl0 = wm + (mf << 4) + (lr << 2);   // 0..63 (j/row local)
                #pragma unroll
                for (int r = 0; r < 4; r++) {
                    float vv = acc[mf][nf][r];
                    if (comp == 0) vv *= scale_q;
                    else if (comp == 1) vv *= scale_k;
                    else if (comp == 3) vv = 1.f / (1.f + __expf(-(vv + bg[(nh << 6) + cl])));
                    ushort uv = f2bf(vv);
                    if (comp == 2) Tb[cl * 72 + rl0 + r]    = uv;   // [col][j]
                    else           Tb[(rl0 + r) * 72 + cl]  = uv;   // [row][col]
                }
            }
            __syncthreads();
            const ushort* srcp = &Tb[orow * 72 + oc];
            if (comp == 2) {
                int c = (nh << 6) + orow;   // global v-col
                ushort* dst = vt + ((size_t)(c >> 5) * 12288 + (size_t)n_blk * 32 + (c & 31)) * 384
                                 + jb + oc;
                *(int4*)dst       = *(const int4*)srcp;
                *(int4*)(dst + 8) = *(const int4*)(srcp + 8);
            } else {
                ushort* outp = (comp == 0) ? qo : (comp == 1) ? ko : go;
                ushort* dst = outp + (size_t)(m0 + orow) * CDIM + (nh << 6) + oc;
                *(int4*)dst       = *(const int4*)srcp;
                *(int4*)(dst + 8) = *(const int4*)(srcp + 8);
            }
        }
    }
}

// ------- tied scores (verified round-7 3D grid): partial[cz,h,i,j] -------
__global__ __launch_bounds__(256) void score128(const ushort* __restrict__ Q,
    const ushort* __restrict__ Kb, float* __restrict__ partial)
{
    __shared__ ushort As[128*128];
    __shared__ ushort Bs[128*128];
    int t = threadIdx.x, l = t & 63, wv = t >> 6;
    int ti = blockIdx.x / 3, tj = blockIdx.x % 3;
    int h = blockIdx.y, cz = blockIdx.z;
    int i0 = ti << 7, j0 = tj << 7;
    int wm = (wv >> 1) << 6, wn = (wv & 1) << 6;
    int sr = t >> 1, half = t & 1;
    f32x4 acc[4][4] = {};
    for (int it = 0; it < 12; it++) {
        if (it) __syncthreads();
        int nb = cz * 48 + (it << 2);
        #pragma unroll
        for (int e = 0; e < 2; e++) {
            int nq = (half << 1) + e;
            const ushort* qp = Q  + ((size_t)(nb + nq) * LDIM + i0 + sr) * CDIM + (h << 5);
            const ushort* kp = Kb + ((size_t)(nb + nq) * LDIM + j0 + sr) * CDIM + (h << 5);
            *(int4*)((char*)As + swz256(sr, (nq << 6) +  0)) = *(const int4*)qp;
            *(int4*)((char*)As + swz256(sr, (nq << 6) + 16)) = *(const int4*)(qp + 8);
            *(int4*)((char*)As + swz256(sr, (nq << 6) + 32)) = *(const int4*)(qp + 16);
            *(int4*)((char*)As + swz256(sr, (nq << 6) + 48)) = *(const int4*)(qp + 24);
            *(int4*)((char*)Bs + swz256(sr, (nq << 6) +  0)) = *(const int4*)kp;
            *(int4*)((char*)Bs + swz256(sr, (nq << 6) + 16)) = *(const int4*)(kp + 8);
            *(int4*)((char*)Bs + swz256(sr, (nq << 6) + 32)) = *(const int4*)(kp + 16);
            *(int4*)((char*)Bs + swz256(sr, (nq << 6) + 48)) = *(const int4*)(kp + 24);
        }
        __syncthreads();
        #pragma unroll
        for (int ks = 0; ks < 4; ks++) {
            int kb = (ks << 6) + ((l >> 4) << 4);
            bf16x8 a[4], b[4];
            #pragma unroll
            for (int x = 0; x < 4; x++) {
                a[x] = *(const bf16x8*)((char*)As + swz256(wm + (x << 4) + (l & 15), kb));
                b[x] = *(const bf16x8*)((char*)Bs + swz256(wn + (x << 4) + (l & 15), kb));
            }
            #pragma unroll
            for (int i = 0; i < 4; i++)
            #pragma unroll
            for (int j = 0; j < 4; j++)
                acc[i][j] = __builtin_amdgcn_mfma_f32_16x16x32_bf16(a[i], b[j], acc[i][j], 0, 0, 0);
        }
    }
    #pragma unroll
    for (int mf = 0; mf < 4; mf++)
    #pragma unroll
    for (int nf = 0; nf < 4; nf++) {
        int j = j0 + wn + (nf << 4) + (l & 15);
        int i = i0 + wm + (mf << 4) + ((l >> 4) << 2);
        #pragma unroll
        for (int r = 0; r < 4; r++)
            partial[((size_t)(cz*HN + h)*LDIM + i + r)*LDIM + j] = acc[mf][nf][r];
    }
}

// ---------------- softmax over j (chunk reduce + bias) -> bf16 ----------------
__global__ __launch_bounds__(64) void softmax_kernel(
    const float* __restrict__ partial, const float* __restrict__ battn, ushort* __restrict__ attn)
{
    int hi = blockIdx.x;
    int l = threadIdx.x;
    float s[6];
    #pragma unroll
    for (int u = 0; u < 6; u++) {
        size_t idx = (size_t)hi * LDIM + l + (u << 6);
        float v = battn[idx];
        #pragma unroll
        for (int c = 0; c < NCHUNK; c++) v += partial[(size_t)c * HN * LL + idx];
        s[u] = v;
    }
    float m = s[0];
    #pragma unroll
    for (int u = 1; u < 6; u++) m = fmaxf(m, s[u]);
    #pragma unroll
    for (int off = 32; off; off >>= 1) m = fmaxf(m, __shfl_xor(m, off, 64));
    float sum = 0.f;
    #pragma unroll
    for (int u = 0; u < 6; u++) { s[u] = __expf(s[u] - m); sum += s[u]; }
    #pragma unroll
    for (int off = 32; off; off >>= 1) sum += __shfl_xor(sum, off, 64);
    float inv = 1.f / sum;
    #pragma unroll
    for (int u = 0; u < 6; u++) attn[(size_t)hi * LDIM + l + (u << 6)] = f2bf(s[u] * inv);
}

// ------- PV per-head GEMM (BK=64): pvout[(n,i),h*32+d] -------
__global__ __launch_bounds__(256) void pvg_gemm(const ushort* __restrict__ attn,
    const ushort* __restrict__ vt, ushort* __restrict__ pvout)
{
    __shared__ ushort As[128*64];
    __shared__ ushort Ws[128*64];
    int t = threadIdx.x, l = t & 63, wv = t >> 6;
    int n0 = blockIdx.x << 7;
    int i0 = blockIdx.y << 7;
    int h  = blockIdx.z;
    const ushort* abase = attn + (size_t)h * LL;
    const ushort* bbase = vt + (size_t)h * VTPLANE;
    int wm = (wv >> 1) << 6, wn = (wv & 1) << 6;
    int sr = t >> 1, sh = (t & 1) << 5;
    f32x4 acc[4][4] = {};
    for (int k0 = 0; k0 < LDIM; k0 += 64) {
        if (k0) __syncthreads();
        {
            const ushort* ap = abase + (size_t)(i0 + sr) * LDIM + k0 + sh;
            const ushort* bp = bbase + (size_t)(n0 + sr) * LDIM + k0 + sh;
            #pragma unroll
            for (int u = 0; u < 4; u++) {
                *(int4*)((char*)As + swz128(sr, (sh << 1) + (u << 4))) = *(const int4*)(ap + (u << 3));
                *(int4*)((char*)Ws + swz128(sr, (sh << 1) + (u << 4))) = *(const int4*)(bp + (u << 3));
            }
        }
        __syncthreads();
        #pragma unroll
        for (int ks = 0; ks < 2; ks++) {
            int kb = (ks << 6) + ((l >> 4) << 4);
            bf16x8 a[4], b[4];
            #pragma unroll
            for (int x = 0; x < 4; x++) {
                a[x] = *(const bf16x8*)((char*)As + swz128(wm + (x << 4) + (l & 15), kb));
                b[x] = *(const bf16x8*)((char*)Ws + swz128(wn + (x << 4) + (l & 15), kb));
            }
            #pragma unroll
            for (int i = 0; i < 4; i++)
            #pragma unroll
            for (int j = 0; j < 4; j++)
                acc[i][j] = __builtin_amdgcn_mfma_f32_16x16x32_bf16(a[i], b[j], acc[i][j], 0, 0, 0);
        }
    }
    #pragma unroll
    for (int mf = 0; mf < 4; mf++)
    #pragma unroll
    for (int nf = 0; nf < 4; nf++) {
        int col  = n0 + wn + (nf << 4) + (l & 15);
        int row0 = i0 + wm + (mf << 4) + ((l >> 4) << 2);
        int n = col >> 5, d = col & 31;
        #pragma unroll
        for (int r = 0; r < 4; r++) {
            int i = row0 + r;
            pvout[((size_t)n * LDIM + i) * CDIM + (h << 5) + d] = f2bf(acc[mf][nf][r]);
        }
    }
}

extern "C" void kernel_launch(void* const* d_in, const int* in_sizes, int n_in,
                              void* d_out, int out_size, void* d_ws, size_t ws_size,
                              hipStream_t stream)
{
    const float* pair     = (const float*)d_in[0];
    const float* rbf_feat = (const float*)d_in[1];
    const float* emb_b    = (const float*)d_in[3];
    const float* proj_b   = (const float*)d_in[5];
    const float* ff_ln_w  = (const float*)d_in[30];
    const float* ff_ln_b  = (const float*)d_in[31];
    const float* ff_b1    = (const float*)d_in[33];
    const float* ff_b2    = (const float*)d_in[35];
    float* out = (float*)d_out;

    ushort* R0 = (ushort*)d_ws;
    ushort* R1 = R0 + (size_t)LL*CDIM;
    ushort* R2 = R1 + (size_t)LL*CDIM;
    ushort* R3 = R2 + (size_t)LL*CDIM;
    float*  partialb = (float*)(R3 + (size_t)LL*CDIM);
    float*  battn_r  = partialb + (size_t)NCHUNK*HN*LL;
    float*  battn_c  = battn_r  + (size_t)HN*LL;
    ushort* attn_bf  = (ushort*)(battn_c + (size_t)HN*LL);
    ushort* wt       = attn_bf + (size_t)HN*LL;

    size_t need_bytes = (size_t)4*LL*CDIM*2 + ((size_t)NCHUNK*HN*LL + 2*(size_t)HN*LL)*4
                      + (size_t)HN*LL*2 + (size_t)262144*2;
    if (ws_size < need_bytes) return;

    const size_t WS = 16384;
    ushort* wt_emb  = wt;
    ushort* wt_proj = wt + WS;
    ushort* wt_ff1  = wt + 12*WS;
    ushort* wt_ff2  = wt + 12*WS + 32768;

    const float SCALE = 0.17677669529663687f;  // 32^-0.5

    wprep_kernel<<<dim3(128, 14), 256, 0, stream>>>(wt,
        (const float*)d_in[2], (const float*)d_in[4],
        (const float*)d_in[10], (const float*)d_in[11], (const float*)d_in[12],
        (const float*)d_in[14], (const float*)d_in[16],
        (const float*)d_in[22], (const float*)d_in[23], (const float*)d_in[24],
        (const float*)d_in[26], (const float*)d_in[28],
        (const float*)d_in[32], (const float*)d_in[34]);

    // emb hidden bf16 -> R3
    mgemm64<1,0,1,0><<<dim3(1,LL/64), 256, 0, stream>>>(rbf_feat, wt_emb, emb_b, nullptr, nullptr, R3,
        nullptr, nullptr, nullptr, 128, 128, 36, 1.f, 0, 0);
    // fused proj + dual battn: rbf never materialized
    proj_battn_gemm<<<1152, 256, 0, stream>>>(R3, wt_proj, proj_b,
        (const float*)d_in[8],  (const float*)d_in[9],  (const float*)d_in[13],
        (const float*)d_in[20], (const float*)d_in[21], (const float*)d_in[25],
        battn_r, battn_c);

    // initial row-pass xln (transposed frame) -> R3
    lnpack_kernel<<<LL/4, 256, 0, stream>>>(pair, R3, (const float*)d_in[6], (const float*)d_in[7], 1);

    ushort* XLN = R3;
    for (int pass = 0; pass < 2; pass++) {
        const float* const* wp = (const float* const*)(d_in + (pass ? 18 : 6));
        int trans = pass ? 0 : 1;
        const float* P = pass ? (const float*)out : pair;
        const float* battnb = pass ? battn_c : battn_r;
        int ws0 = pass ? 7 : 2;
        const float* nlw = pass ? ff_ln_w : (const float*)d_in[18];
        const float* nlb = pass ? ff_ln_b : (const float*)d_in[19];
        ushort* Qb   = R0;
        ushort* Kb2  = pass ? R3 : R1;
        ushort* VTb  = R2;
        ushort* PVb  = R0;
        ushort* XLNn = pass ? R3 : R1;
        qkv4_gemm<<<LL/64, 256, 0, stream>>>(XLN, wt + ws0*WS, Qb, Kb2, VTb, XLN, wp[9], SCALE, 1.f/LDIM);
        score128<<<dim3(9, HN, NCHUNK), 256, 0, stream>>>(Qb, Kb2, partialb);
        softmax_kernel<<<HN*LDIM, 64, 0, stream>>>(partialb, battnb, attn_bf);
        pvg_gemm<<<dim3(96, 3, 4), 256, 0, stream>>>(attn_bf, VTb, PVb);
        mgemm64<0,2,3,1><<<dim3(1,LL/64), 256, 0, stream>>>(PVb, wt + (ws0+4)*WS, wp[11], XLN, P, out,
            nlw, nlb, XLNn, 128, 128, 128, 1.f, trans, trans);
        XLN = XLNn;
    }

    // FFN: out += relu(xln@w1+b1)@w2+b2  (h1 bf16 [LL][256] spans R0+R1)
    mgemm64<1,1,1,0><<<dim3(2,LL/64), 256, 0, stream>>>(XLN, wt_ff1, ff_b1, nullptr, nullptr, R0,
        nullptr, nullptr, nullptr, 256, 128, 128, 1.f, 0, 0);
    mgemm64<0,1,0,0><<<dim3(1,LL/64), 256, 0, stream>>>(R0, wt_ff2, ff_b2, nullptr, out, out,
        nullptr, nullptr, nullptr, 128, 256, 256, 1.f, 0, 0);
}